// Round 1
// baseline (7924.897 us; speedup 1.0000x reference)
//
#include <hip/hip_runtime.h>

#define N_NODES 40000
#define E_EDGES 640000
#define DIM 128

// ---------------------------------------------------------------------------
// SpMM: y[rows[e], :] += vals[e] * x[cols[e], :]
// 32 lanes per edge, float4 per lane (128 floats per row).
// ---------------------------------------------------------------------------
__global__ __launch_bounds__(256) void spmm_kernel(
    const int* __restrict__ rows, const int* __restrict__ cols,
    const float* __restrict__ vals, const float* __restrict__ x,
    float* __restrict__ y, int E)
{
    int eid = blockIdx.x * 8 + (threadIdx.x >> 5);
    if (eid >= E) return;
    int lane = threadIdx.x & 31;
    int r = rows[eid];
    int c = cols[eid];
    float v = vals[eid];
    float4 xv = ((const float4*)(x + (size_t)c * DIM))[lane];
    float* yp = y + (size_t)r * DIM + lane * 4;
    unsafeAtomicAdd(yp + 0, v * xv.x);
    unsafeAtomicAdd(yp + 1, v * xv.y);
    unsafeAtomicAdd(yp + 2, v * xv.z);
    unsafeAtomicAdd(yp + 3, v * xv.w);
}

// ---------------------------------------------------------------------------
// Elementwise fusions (float4 over N*D)
// ---------------------------------------------------------------------------
__device__ __forceinline__ float4 f4mul(float4 a, float4 b) {
    return make_float4(a.x*b.x, a.y*b.y, a.z*b.z, a.w*b.w);
}
__device__ __forceinline__ float4 f4add(float4 a, float4 b) {
    return make_float4(a.x+b.x, a.y+b.y, a.z+b.z, a.w+b.w);
}

// Layer A hop0: sml = a*xl; smr = b*xr; kl = a + sml; kr = b + smr
__global__ __launch_bounds__(256) void ew_hop0_kernel(
    const float4* __restrict__ a, const float4* __restrict__ b,
    const float4* __restrict__ xl, const float4* __restrict__ xr,
    float4* __restrict__ sml, float4* __restrict__ smr,
    float4* __restrict__ kl, float4* __restrict__ kr, int n4)
{
    int i = blockIdx.x * 256 + threadIdx.x;
    if (i >= n4) return;
    float4 av = a[i], bv = b[i], lv = xl[i], rv = xr[i];
    float4 ml = f4mul(av, lv);
    float4 mr = f4mul(bv, rv);
    sml[i] = ml; smr[i] = mr;
    kl[i] = f4add(av, ml);
    kr[i] = f4add(bv, mr);
}

// Layer A hop1: sal += a1; sml += a1*kl; sbr += b1; smr += b1*kr
__global__ __launch_bounds__(256) void ew_hop1_kernel(
    const float4* __restrict__ a1, const float4* __restrict__ b1,
    const float4* __restrict__ kl, const float4* __restrict__ kr,
    float4* __restrict__ sal, float4* __restrict__ sml,
    float4* __restrict__ sbr, float4* __restrict__ smr, int n4)
{
    int i = blockIdx.x * 256 + threadIdx.x;
    if (i >= n4) return;
    float4 a1v = a1[i], b1v = b1[i], klv = kl[i], krv = kr[i];
    sal[i] = f4add(sal[i], a1v);
    sml[i] = f4add(sml[i], f4mul(a1v, klv));
    sbr[i] = f4add(sbr[i], b1v);
    smr[i] = f4add(smr[i], f4mul(b1v, krv));
}

// Layer B hop0: sml = a*y1; kl = a + sml; kr = b + b*z1
__global__ __launch_bounds__(256) void ew_b0_kernel(
    const float4* __restrict__ a, const float4* __restrict__ b,
    const float4* __restrict__ y1, const float4* __restrict__ z1,
    float4* __restrict__ sml, float4* __restrict__ kl,
    float4* __restrict__ kr, int n4)
{
    int i = blockIdx.x * 256 + threadIdx.x;
    if (i >= n4) return;
    float4 av = a[i], bv = b[i], yv = y1[i], zv = z1[i];
    float4 ml = f4mul(av, yv);
    sml[i] = ml;
    kl[i] = f4add(av, ml);
    kr[i] = f4add(bv, f4mul(bv, zv));
}

// Layer B hop1: sal += a1; sml += a1*kl
__global__ __launch_bounds__(256) void ew_b1_kernel(
    const float4* __restrict__ a1, const float4* __restrict__ kl,
    float4* __restrict__ sal, float4* __restrict__ sml, int n4)
{
    int i = blockIdx.x * 256 + threadIdx.x;
    if (i >= n4) return;
    float4 a1v = a1[i], klv = kl[i];
    sal[i] = f4add(sal[i], a1v);
    sml[i] = f4add(sml[i], f4mul(a1v, klv));
}

// ---------------------------------------------------------------------------
// Fused double GEMM: out = relu( X1 @ W1^T + X2 @ W2^T + 2*(b1 + b2) )
// X1, X2: [nrows, 128]   W1, W2: [128, 128] row-major (out_j = dot(X[n,:], W[j,:]))
// Block: 256 threads, 64 rows x 128 cols tile. Thread: 8 rows x 4 cols.
// ---------------------------------------------------------------------------
__global__ __launch_bounds__(256) void gemm2_kernel(
    const float* __restrict__ X1, const float* __restrict__ X2,
    const float* __restrict__ W1, const float* __restrict__ W2,
    const float* __restrict__ b1, const float* __restrict__ b2,
    float* __restrict__ out, int nrows)
{
    __shared__ float xs1[64][DIM];   // 32 KB
    __shared__ float xs2[64][DIM];   // 32 KB
    const int row0 = blockIdx.x * 64;
    const int tid = threadIdx.x;

    // stage X tiles: 64*32 float4 per matrix, 256 threads -> 8 float4 each
    for (int i = tid; i < 64 * (DIM / 4); i += 256) {
        int r = i >> 5;          // DIM/4 == 32
        int c4 = i & 31;
        ((float4*)&xs1[r][0])[c4] = ((const float4*)(X1 + (size_t)(row0 + r) * DIM))[c4];
        ((float4*)&xs2[r][0])[c4] = ((const float4*)(X2 + (size_t)(row0 + r) * DIM))[c4];
    }
    __syncthreads();

    const int rg = tid >> 5;     // 0..7  -> rows rg*8 .. rg*8+7
    const int cg = tid & 31;     // 0..31 -> cols cg*4 .. cg*4+3

    float acc[8][4];
    #pragma unroll
    for (int i = 0; i < 8; i++)
        #pragma unroll
        for (int j = 0; j < 4; j++) acc[i][j] = 0.0f;

    for (int k = 0; k < DIM; k += 4) {
        float4 w1v[4], w2v[4];
        #pragma unroll
        for (int j = 0; j < 4; j++) {
            w1v[j] = *(const float4*)(W1 + (size_t)(cg * 4 + j) * DIM + k);
            w2v[j] = *(const float4*)(W2 + (size_t)(cg * 4 + j) * DIM + k);
        }
        #pragma unroll
        for (int i = 0; i < 8; i++) {
            float4 x1 = *(const float4*)(&xs1[rg * 8 + i][k]);
            float4 x2 = *(const float4*)(&xs2[rg * 8 + i][k]);
            #pragma unroll
            for (int j = 0; j < 4; j++) {
                acc[i][j] += x1.x * w1v[j].x + x1.y * w1v[j].y
                           + x1.z * w1v[j].z + x1.w * w1v[j].w
                           + x2.x * w2v[j].x + x2.y * w2v[j].y
                           + x2.z * w2v[j].z + x2.w * w2v[j].w;
            }
        }
    }

    // bias + relu + coalesced float4 store
    float c0 = 2.0f * (b1[cg * 4 + 0] + b2[cg * 4 + 0]);
    float c1 = 2.0f * (b1[cg * 4 + 1] + b2[cg * 4 + 1]);
    float c2 = 2.0f * (b1[cg * 4 + 2] + b2[cg * 4 + 2]);
    float c3 = 2.0f * (b1[cg * 4 + 3] + b2[cg * 4 + 3]);
    #pragma unroll
    for (int i = 0; i < 8; i++) {
        int r = row0 + rg * 8 + i;
        float4 o;
        o.x = fmaxf(acc[i][0] + c0, 0.0f);
        o.y = fmaxf(acc[i][1] + c1, 0.0f);
        o.z = fmaxf(acc[i][2] + c2, 0.0f);
        o.w = fmaxf(acc[i][3] + c3, 0.0f);
        *(float4*)(out + (size_t)r * DIM + cg * 4) = o;
    }
}

// ---------------------------------------------------------------------------
extern "C" void kernel_launch(void* const* d_in, const int* in_sizes, int n_in,
                              void* d_out, int out_size, void* d_ws, size_t ws_size,
                              hipStream_t stream)
{
    const float* l_feat = (const float*)d_in[0];
    const float* r_feat = (const float*)d_in[1];
    const int*   rows   = (const int*)d_in[2];
    const int*   cols   = (const int*)d_in[3];
    const float* vals   = (const float*)d_in[4];
    const float* W1a    = (const float*)d_in[5];
    const float* b1a    = (const float*)d_in[6];
    const float* W2a    = (const float*)d_in[7];
    const float* b2a    = (const float*)d_in[8];
    const float* W1b    = (const float*)d_in[9];
    const float* b1b    = (const float*)d_in[10];
    const float* W2b    = (const float*)d_in[11];
    const float* b2b    = (const float*)d_in[12];
    float* out = (float*)d_out;

    const size_t NT = (size_t)N_NODES * DIM;
    float* buf = (float*)d_ws;
    float* B0 = buf;            // a0 / SaL accumulator
    float* B1 = buf + NT;       // b0 / SbR accumulator
    float* B2 = buf + 2 * NT;   // SmL accumulator
    float* B3 = buf + 3 * NT;   // SmR accumulator / a1b (layer B)
    float* B4 = buf + 4 * NT;   // Kl -> y1
    float* B5 = buf + 5 * NT;   // Kr -> z1
    float* B6 = buf + 6 * NT;   // a1 / Klb (layer B)
    float* B7 = out;            // b1' (layer A) / Krb (layer B) -- final gemm overwrites

    const int n4 = (int)(NT / 4);
    dim3 blk(256);
    dim3 ewGrid((n4 + 255) / 256);
    dim3 spGrid((E_EDGES + 7) / 8);
    dim3 gmGrid(N_NODES / 64);

    // ======================= Layer A =======================
    hipMemsetAsync(B0, 0, NT * sizeof(float), stream);
    hipMemsetAsync(B1, 0, NT * sizeof(float), stream);
    // a0 = A @ r_feat ; b0 = A^T @ l_feat
    spmm_kernel<<<spGrid, blk, 0, stream>>>(rows, cols, vals, r_feat, B0, E_EDGES);
    spmm_kernel<<<spGrid, blk, 0, stream>>>(cols, rows, vals, l_feat, B1, E_EDGES);
    // lm0, rm0, Kl1, Kr1
    ew_hop0_kernel<<<ewGrid, blk, 0, stream>>>(
        (const float4*)B0, (const float4*)B1,
        (const float4*)l_feat, (const float4*)r_feat,
        (float4*)B2, (float4*)B3, (float4*)B4, (float4*)B5, n4);
    hipMemsetAsync(B6, 0, NT * sizeof(float), stream);
    hipMemsetAsync(B7, 0, NT * sizeof(float), stream);
    // a1 = A @ Kr1 ; b1' = A^T @ Kl1
    spmm_kernel<<<spGrid, blk, 0, stream>>>(rows, cols, vals, B5, B6, E_EDGES);
    spmm_kernel<<<spGrid, blk, 0, stream>>>(cols, rows, vals, B4, B7, E_EDGES);
    ew_hop1_kernel<<<ewGrid, blk, 0, stream>>>(
        (const float4*)B6, (const float4*)B7,
        (const float4*)B4, (const float4*)B5,
        (float4*)B0, (float4*)B2, (float4*)B1, (float4*)B3, n4);
    // y1 = relu(SaL@W1a^T + SmL@W2a^T + 2(b1a+b2a)) ; z1 likewise from SbR,SmR
    gemm2_kernel<<<gmGrid, blk, 0, stream>>>(B0, B2, W1a, W2a, b1a, b2a, B4, N_NODES);
    gemm2_kernel<<<gmGrid, blk, 0, stream>>>(B1, B3, W1a, W2a, b1a, b2a, B5, N_NODES);

    // ======================= Layer B (only l-output needed) =======================
    hipMemsetAsync(B0, 0, NT * sizeof(float), stream);
    hipMemsetAsync(B1, 0, NT * sizeof(float), stream);
    // a0b = A @ z1 ; b0b = A^T @ y1
    spmm_kernel<<<spGrid, blk, 0, stream>>>(rows, cols, vals, B5, B0, E_EDGES);
    spmm_kernel<<<spGrid, blk, 0, stream>>>(cols, rows, vals, B4, B1, E_EDGES);
    // SmL = a0b*y1; Klb = a0b + SmL; Krb = b0b + b0b*z1
    ew_b0_kernel<<<ewGrid, blk, 0, stream>>>(
        (const float4*)B0, (const float4*)B1,
        (const float4*)B4, (const float4*)B5,
        (float4*)B2, (float4*)B6, (float4*)B7, n4);
    hipMemsetAsync(B3, 0, NT * sizeof(float), stream);
    // a1b = A @ Krb
    spmm_kernel<<<spGrid, blk, 0, stream>>>(rows, cols, vals, B7, B3, E_EDGES);
    ew_b1_kernel<<<ewGrid, blk, 0, stream>>>(
        (const float4*)B3, (const float4*)B6,
        (float4*)B0, (float4*)B2, n4);
    // out = relu(SaL@W1b^T + SmL@W2b^T + 2(b1b+b2b))
    gemm2_kernel<<<gmGrid, blk, 0, stream>>>(B0, B2, W1b, W2b, b1b, b2b, out, N_NODES);
}

// Round 2
// 942.701 us; speedup vs baseline: 8.4066x; 8.4066x over previous
//
#include <hip/hip_runtime.h>

#define N_NODES 40000
#define E_EDGES 640000
#define DIM 128

// ===========================================================================
// CSR build: histogram -> exclusive scan -> scatter (col,val) packed
// ===========================================================================
__global__ __launch_bounds__(256) void hist_kernel(
    const int* __restrict__ rows, const int* __restrict__ cols,
    int* __restrict__ cntA, int* __restrict__ cntT, int E)
{
    int e = blockIdx.x * 256 + threadIdx.x;
    if (e >= E) return;
    atomicAdd(&cntA[rows[e]], 1);
    atomicAdd(&cntT[cols[e]], 1);
}

// single-block exclusive scan of counts[n] -> rowptr[0..n]
__global__ __launch_bounds__(1024) void scan_kernel(
    const int* __restrict__ counts, int* __restrict__ rowptr, int n)
{
    __shared__ int wsum[16];
    __shared__ int running_s;
    const int tid = threadIdx.x;
    const int lane = tid & 63;
    const int wid = tid >> 6;
    if (tid == 0) running_s = 0;
    __syncthreads();
    for (int base = 0; base < n; base += 1024) {
        int i = base + tid;
        int v = (i < n) ? counts[i] : 0;
        int incl = v;
        #pragma unroll
        for (int off = 1; off < 64; off <<= 1) {
            int t = __shfl_up(incl, off, 64);
            if (lane >= off) incl += t;
        }
        if (lane == 63) wsum[wid] = incl;
        __syncthreads();
        int run = running_s;
        if (wid == 0) {
            int w = (lane < 16) ? wsum[lane] : 0;
            int wincl = w;
            #pragma unroll
            for (int off = 1; off < 16; off <<= 1) {
                int t = __shfl_up(wincl, off, 64);
                if (lane >= off) wincl += t;
            }
            if (lane < 16) wsum[lane] = wincl - w;   // exclusive wave offsets
        }
        __syncthreads();
        int excl = run + wsum[wid] + (incl - v);
        if (i < n) rowptr[i] = excl;
        __syncthreads();                              // all reads of wsum done
        if (tid == 1023) running_s = run + wsum[15] + incl;
        __syncthreads();
    }
    if (tid == 0) rowptr[n] = running_s;
}

__global__ __launch_bounds__(256) void scatter_kernel(
    const int* __restrict__ rows, const int* __restrict__ cols,
    const float* __restrict__ vals,
    int* __restrict__ curA, int* __restrict__ curT,
    int2* __restrict__ colvalA, int2* __restrict__ colvalT, int E)
{
    int e = blockIdx.x * 256 + threadIdx.x;
    if (e >= E) return;
    int r = rows[e], c = cols[e];
    int v = __float_as_int(vals[e]);
    int pA = atomicAdd(&curA[r], 1);
    colvalA[pA] = make_int2(c, v);
    int pT = atomicAdd(&curT[c], 1);
    colvalT[pT] = make_int2(r, v);
}

// ===========================================================================
// Pull SpMM: one wave per row, float2 per lane. y[row,:] = sum v * x[col,:]
// ===========================================================================
__global__ __launch_bounds__(256) void spmm_pull(
    const int* __restrict__ rowptr, const int2* __restrict__ colval,
    const float* __restrict__ x, float* __restrict__ y)
{
    int row = blockIdx.x * 4 + (threadIdx.x >> 6);
    if (row >= N_NODES) return;
    int lane2 = (threadIdx.x & 63) * 2;
    int s = rowptr[row], e = rowptr[row + 1];
    float2 acc = make_float2(0.f, 0.f);
    int i = s;
    for (; i + 2 <= e; i += 2) {
        int2 cv0 = colval[i], cv1 = colval[i + 1];
        float2 xv0 = *(const float2*)(x + (size_t)cv0.x * DIM + lane2);
        float2 xv1 = *(const float2*)(x + (size_t)cv1.x * DIM + lane2);
        float v0 = __int_as_float(cv0.y), v1 = __int_as_float(cv1.y);
        acc.x = fmaf(v0, xv0.x, acc.x); acc.y = fmaf(v0, xv0.y, acc.y);
        acc.x = fmaf(v1, xv1.x, acc.x); acc.y = fmaf(v1, xv1.y, acc.y);
    }
    if (i < e) {
        int2 cv = colval[i];
        float2 xv = *(const float2*)(x + (size_t)cv.x * DIM + lane2);
        float v = __int_as_float(cv.y);
        acc.x = fmaf(v, xv.x, acc.x); acc.y = fmaf(v, xv.y, acc.y);
    }
    *(float2*)(y + (size_t)row * DIM + lane2) = acc;
}

// t = A@x (pull); then p += t; q += t * z   (fuses hop-1 elementwise accum)
__global__ __launch_bounds__(256) void spmm_acc2(
    const int* __restrict__ rowptr, const int2* __restrict__ colval,
    const float* __restrict__ x, float* __restrict__ p,
    float* __restrict__ q, const float* __restrict__ z)
{
    int row = blockIdx.x * 4 + (threadIdx.x >> 6);
    if (row >= N_NODES) return;
    int lane2 = (threadIdx.x & 63) * 2;
    int s = rowptr[row], e = rowptr[row + 1];
    float2 acc = make_float2(0.f, 0.f);
    int i = s;
    for (; i + 2 <= e; i += 2) {
        int2 cv0 = colval[i], cv1 = colval[i + 1];
        float2 xv0 = *(const float2*)(x + (size_t)cv0.x * DIM + lane2);
        float2 xv1 = *(const float2*)(x + (size_t)cv1.x * DIM + lane2);
        float v0 = __int_as_float(cv0.y), v1 = __int_as_float(cv1.y);
        acc.x = fmaf(v0, xv0.x, acc.x); acc.y = fmaf(v0, xv0.y, acc.y);
        acc.x = fmaf(v1, xv1.x, acc.x); acc.y = fmaf(v1, xv1.y, acc.y);
    }
    if (i < e) {
        int2 cv = colval[i];
        float2 xv = *(const float2*)(x + (size_t)cv.x * DIM + lane2);
        float v = __int_as_float(cv.y);
        acc.x = fmaf(v, xv.x, acc.x); acc.y = fmaf(v, xv.y, acc.y);
    }
    size_t off = (size_t)row * DIM + lane2;
    float2 pv = *(float2*)(p + off);
    float2 qv = *(float2*)(q + off);
    float2 zv = *(const float2*)(z + off);
    pv.x += acc.x; pv.y += acc.y;
    qv.x += acc.x * zv.x; qv.y += acc.y * zv.y;
    *(float2*)(p + off) = pv;
    *(float2*)(q + off) = qv;
}

// ===========================================================================
// Elementwise fusions
// ===========================================================================
__device__ __forceinline__ float4 f4mul(float4 a, float4 b) {
    return make_float4(a.x*b.x, a.y*b.y, a.z*b.z, a.w*b.w);
}
__device__ __forceinline__ float4 f4add(float4 a, float4 b) {
    return make_float4(a.x+b.x, a.y+b.y, a.z+b.z, a.w+b.w);
}

// Layer A hop0: sml = a*xl; smr = b*xr; kl = a + sml; kr = b + smr
__global__ __launch_bounds__(256) void ew_hop0_kernel(
    const float4* __restrict__ a, const float4* __restrict__ b,
    const float4* __restrict__ xl, const float4* __restrict__ xr,
    float4* __restrict__ sml, float4* __restrict__ smr,
    float4* __restrict__ kl, float4* __restrict__ kr, int n4)
{
    int i = blockIdx.x * 256 + threadIdx.x;
    if (i >= n4) return;
    float4 av = a[i], bv = b[i], lv = xl[i], rv = xr[i];
    float4 ml = f4mul(av, lv);
    float4 mr = f4mul(bv, rv);
    sml[i] = ml; smr[i] = mr;
    kl[i] = f4add(av, ml);
    kr[i] = f4add(bv, mr);
}

// Layer B hop0: sm = a*y1; kl = a + sm; krb = b + b*z1  (krb aliases b!)
__global__ __launch_bounds__(256) void ew_b0_kernel(
    const float4* __restrict__ a, const float4* b,
    const float4* __restrict__ y1, const float4* __restrict__ z1,
    float4* __restrict__ sm, float4* __restrict__ kl,
    float4* krb, int n4)
{
    int i = blockIdx.x * 256 + threadIdx.x;
    if (i >= n4) return;
    float4 av = a[i], bv = b[i], yv = y1[i], zv = z1[i];
    float4 ml = f4mul(av, yv);
    sm[i] = ml;
    kl[i] = f4add(av, ml);
    krb[i] = f4add(bv, f4mul(bv, zv));
}

// ===========================================================================
// Fused double GEMM: out = relu( X1 @ W1^T + X2 @ W2^T + 2*(b1 + b2) )
// ===========================================================================
__global__ __launch_bounds__(256) void gemm2_kernel(
    const float* __restrict__ X1, const float* __restrict__ X2,
    const float* __restrict__ W1, const float* __restrict__ W2,
    const float* __restrict__ b1, const float* __restrict__ b2,
    float* __restrict__ out, int nrows)
{
    __shared__ float xs1[64][DIM];
    __shared__ float xs2[64][DIM];
    const int row0 = blockIdx.x * 64;
    const int tid = threadIdx.x;

    for (int i = tid; i < 64 * (DIM / 4); i += 256) {
        int r = i >> 5;
        int c4 = i & 31;
        ((float4*)&xs1[r][0])[c4] = ((const float4*)(X1 + (size_t)(row0 + r) * DIM))[c4];
        ((float4*)&xs2[r][0])[c4] = ((const float4*)(X2 + (size_t)(row0 + r) * DIM))[c4];
    }
    __syncthreads();

    const int rg = tid >> 5;
    const int cg = tid & 31;

    float acc[8][4];
    #pragma unroll
    for (int i = 0; i < 8; i++)
        #pragma unroll
        for (int j = 0; j < 4; j++) acc[i][j] = 0.0f;

    for (int k = 0; k < DIM; k += 4) {
        float4 w1v[4], w2v[4];
        #pragma unroll
        for (int j = 0; j < 4; j++) {
            w1v[j] = *(const float4*)(W1 + (size_t)(cg * 4 + j) * DIM + k);
            w2v[j] = *(const float4*)(W2 + (size_t)(cg * 4 + j) * DIM + k);
        }
        #pragma unroll
        for (int i = 0; i < 8; i++) {
            float4 x1 = *(const float4*)(&xs1[rg * 8 + i][k]);
            float4 x2 = *(const float4*)(&xs2[rg * 8 + i][k]);
            #pragma unroll
            for (int j = 0; j < 4; j++) {
                acc[i][j] += x1.x * w1v[j].x + x1.y * w1v[j].y
                           + x1.z * w1v[j].z + x1.w * w1v[j].w
                           + x2.x * w2v[j].x + x2.y * w2v[j].y
                           + x2.z * w2v[j].z + x2.w * w2v[j].w;
            }
        }
    }

    float c0 = 2.0f * (b1[cg * 4 + 0] + b2[cg * 4 + 0]);
    float c1 = 2.0f * (b1[cg * 4 + 1] + b2[cg * 4 + 1]);
    float c2 = 2.0f * (b1[cg * 4 + 2] + b2[cg * 4 + 2]);
    float c3 = 2.0f * (b1[cg * 4 + 3] + b2[cg * 4 + 3]);
    #pragma unroll
    for (int i = 0; i < 8; i++) {
        int r = row0 + rg * 8 + i;
        float4 o;
        o.x = fmaxf(acc[i][0] + c0, 0.0f);
        o.y = fmaxf(acc[i][1] + c1, 0.0f);
        o.z = fmaxf(acc[i][2] + c2, 0.0f);
        o.w = fmaxf(acc[i][3] + c3, 0.0f);
        *(float4*)(out + (size_t)r * DIM + cg * 4) = o;
    }
}

// ===========================================================================
extern "C" void kernel_launch(void* const* d_in, const int* in_sizes, int n_in,
                              void* d_out, int out_size, void* d_ws, size_t ws_size,
                              hipStream_t stream)
{
    const float* l_feat = (const float*)d_in[0];
    const float* r_feat = (const float*)d_in[1];
    const int*   rows   = (const int*)d_in[2];
    const int*   cols   = (const int*)d_in[3];
    const float* vals   = (const float*)d_in[4];
    const float* W1a    = (const float*)d_in[5];
    const float* b1a    = (const float*)d_in[6];
    const float* W2a    = (const float*)d_in[7];
    const float* b2a    = (const float*)d_in[8];
    const float* W1b    = (const float*)d_in[9];
    const float* b1b    = (const float*)d_in[10];
    const float* W2b    = (const float*)d_in[11];
    const float* b2b    = (const float*)d_in[12];
    float* out = (float*)d_out;

    const size_t NT = (size_t)N_NODES * DIM;
    char* ws = (char*)d_ws;
    float* F0 = (float*)ws;
    float* F1 = F0 + NT;
    float* F2 = F1 + NT;
    float* F3 = F2 + NT;
    float* F4 = F3 + NT;
    float* F5 = F4 + NT;
    char* p = (char*)(F5 + NT);
    int* rowptrA = (int*)p;             p += (size_t)(N_NODES + 1) * 4;
    int* rowptrT = (int*)p;             p += (size_t)(N_NODES + 1) * 4;
    int* curA    = (int*)p;             p += (size_t)N_NODES * 4;
    int* curT    = (int*)p;             p += (size_t)N_NODES * 4;
    int2* colvalA = (int2*)p;           p += (size_t)E_EDGES * 8;
    int2* colvalT = (int2*)p;

    const int n4 = (int)(NT / 4);
    dim3 blk(256);
    dim3 ewGrid((n4 + 255) / 256);
    dim3 eGrid((E_EDGES + 255) / 256);
    dim3 spGrid((N_NODES + 3) / 4);
    dim3 gmGrid(N_NODES / 64);

    // ---- build CSR for A (rows->cols) and A^T (cols->rows) ----
    hipMemsetAsync(curA, 0, (size_t)N_NODES * 4, stream);
    hipMemsetAsync(curT, 0, (size_t)N_NODES * 4, stream);
    hist_kernel<<<eGrid, blk, 0, stream>>>(rows, cols, curA, curT, E_EDGES);
    scan_kernel<<<1, 1024, 0, stream>>>(curA, rowptrA, N_NODES);
    scan_kernel<<<1, 1024, 0, stream>>>(curT, rowptrT, N_NODES);
    hipMemcpyAsync(curA, rowptrA, (size_t)N_NODES * 4, hipMemcpyDeviceToDevice, stream);
    hipMemcpyAsync(curT, rowptrT, (size_t)N_NODES * 4, hipMemcpyDeviceToDevice, stream);
    scatter_kernel<<<eGrid, blk, 0, stream>>>(rows, cols, vals, curA, curT,
                                              colvalA, colvalT, E_EDGES);

    // ======================= Layer A =======================
    spmm_pull<<<spGrid, blk, 0, stream>>>(rowptrA, colvalA, r_feat, F0);   // a0
    spmm_pull<<<spGrid, blk, 0, stream>>>(rowptrT, colvalT, l_feat, F1);   // b0
    ew_hop0_kernel<<<ewGrid, blk, 0, stream>>>(
        (const float4*)F0, (const float4*)F1,
        (const float4*)l_feat, (const float4*)r_feat,
        (float4*)F2, (float4*)F3, (float4*)F4, (float4*)F5, n4);
    // t=A@Kr1: SaL+=t, SmL+=t*Kl1 ; t=AT@Kl1: SbR+=t, SmR+=t*Kr1
    spmm_acc2<<<spGrid, blk, 0, stream>>>(rowptrA, colvalA, F5, F0, F2, F4);
    spmm_acc2<<<spGrid, blk, 0, stream>>>(rowptrT, colvalT, F4, F1, F3, F5);
    gemm2_kernel<<<gmGrid, blk, 0, stream>>>(F0, F2, W1a, W2a, b1a, b2a, F4, N_NODES); // y1
    gemm2_kernel<<<gmGrid, blk, 0, stream>>>(F1, F3, W1a, W2a, b1a, b2a, F5, N_NODES); // z1

    // ======================= Layer B (l-output only) =======================
    spmm_pull<<<spGrid, blk, 0, stream>>>(rowptrA, colvalA, F5, F2);       // a0b
    spmm_pull<<<spGrid, blk, 0, stream>>>(rowptrT, colvalT, F4, F3);       // b0b
    // Sm=F0=a0b*y1; Klb=F1=a0b+Sm; Krb=F3=b0b+b0b*z1 (in-place)
    ew_b0_kernel<<<ewGrid, blk, 0, stream>>>(
        (const float4*)F2, (const float4*)F3,
        (const float4*)F4, (const float4*)F5,
        (float4*)F0, (float4*)F1, (float4*)F3, n4);
    // t=A@Krb: Sa(F2)+=t, Sm(F0)+=t*Klb(F1)
    spmm_acc2<<<spGrid, blk, 0, stream>>>(rowptrA, colvalA, F3, F2, F0, F1);
    gemm2_kernel<<<gmGrid, blk, 0, stream>>>(F2, F0, W1b, W2b, b1b, b2b, out, N_NODES);
}

// Round 3
// 671.997 us; speedup vs baseline: 11.7931x; 1.4028x over previous
//
#include <hip/hip_runtime.h>

#define N_NODES 40000
#define E_EDGES 640000
#define DIM 128

typedef __attribute__((ext_vector_type(8))) short short8;
typedef __attribute__((ext_vector_type(4))) float f32x4;

// fp32 -> bf16 with round-to-nearest-even (finite inputs)
__device__ __forceinline__ unsigned short f2bf(float f) {
    unsigned int u = __float_as_uint(f);
    u = u + 0x7FFFu + ((u >> 16) & 1u);
    return (unsigned short)(u >> 16);
}
__device__ __forceinline__ short8 pack_bf8(float4 a, float4 b) {
    short8 r;
    r[0] = (short)f2bf(a.x); r[1] = (short)f2bf(a.y);
    r[2] = (short)f2bf(a.z); r[3] = (short)f2bf(a.w);
    r[4] = (short)f2bf(b.x); r[5] = (short)f2bf(b.y);
    r[6] = (short)f2bf(b.z); r[7] = (short)f2bf(b.w);
    return r;
}

// ===========================================================================
// CSR build
// ===========================================================================
__global__ __launch_bounds__(256) void hist_kernel(
    const int* __restrict__ rows, const int* __restrict__ cols,
    int* __restrict__ cntA, int* __restrict__ cntT, int E)
{
    int e = blockIdx.x * 256 + threadIdx.x;
    if (e >= E) return;
    atomicAdd(&cntA[rows[e]], 1);
    atomicAdd(&cntT[cols[e]], 1);
}

__global__ __launch_bounds__(1024) void scan_kernel(
    const int* __restrict__ counts, int* __restrict__ rowptr, int n)
{
    __shared__ int wsum[16];
    __shared__ int running_s;
    const int tid = threadIdx.x;
    const int lane = tid & 63;
    const int wid = tid >> 6;
    if (tid == 0) running_s = 0;
    __syncthreads();
    for (int base = 0; base < n; base += 1024) {
        int i = base + tid;
        int v = (i < n) ? counts[i] : 0;
        int incl = v;
        #pragma unroll
        for (int off = 1; off < 64; off <<= 1) {
            int t = __shfl_up(incl, off, 64);
            if (lane >= off) incl += t;
        }
        if (lane == 63) wsum[wid] = incl;
        __syncthreads();
        int run = running_s;
        if (wid == 0) {
            int w = (lane < 16) ? wsum[lane] : 0;
            int wincl = w;
            #pragma unroll
            for (int off = 1; off < 16; off <<= 1) {
                int t = __shfl_up(wincl, off, 64);
                if (lane >= off) wincl += t;
            }
            if (lane < 16) wsum[lane] = wincl - w;
        }
        __syncthreads();
        int excl = run + wsum[wid] + (incl - v);
        if (i < n) rowptr[i] = excl;
        __syncthreads();
        if (tid == 1023) running_s = run + wsum[15] + incl;
        __syncthreads();
    }
    if (tid == 0) rowptr[n] = running_s;
}

__global__ __launch_bounds__(256) void scatter_kernel(
    const int* __restrict__ rows, const int* __restrict__ cols,
    const float* __restrict__ vals,
    int* __restrict__ curA, int* __restrict__ curT,
    int2* __restrict__ colvalA, int2* __restrict__ colvalT, int E)
{
    int e = blockIdx.x * 256 + threadIdx.x;
    if (e >= E) return;
    int r = rows[e], c = cols[e];
    int v = __float_as_int(vals[e]);
    int pA = atomicAdd(&curA[r], 1);
    colvalA[pA] = make_int2(c, v);
    int pT = atomicAdd(&curT[c], 1);
    colvalT[pT] = make_int2(r, v);
}

// ===========================================================================
// Pull SpMM row body (unroll 4)
// ===========================================================================
__device__ __forceinline__ float2 spmm_row(
    const int* __restrict__ rowptr, const int2* __restrict__ colval,
    const float* __restrict__ x, int row, int lane2)
{
    int s = rowptr[row], e = rowptr[row + 1];
    float2 acc = make_float2(0.f, 0.f);
    int i = s;
    for (; i + 4 <= e; i += 4) {
        int2 cv0 = colval[i], cv1 = colval[i+1], cv2 = colval[i+2], cv3 = colval[i+3];
        float2 x0 = *(const float2*)(x + (size_t)cv0.x * DIM + lane2);
        float2 x1 = *(const float2*)(x + (size_t)cv1.x * DIM + lane2);
        float2 x2 = *(const float2*)(x + (size_t)cv2.x * DIM + lane2);
        float2 x3 = *(const float2*)(x + (size_t)cv3.x * DIM + lane2);
        float v0 = __int_as_float(cv0.y), v1 = __int_as_float(cv1.y);
        float v2 = __int_as_float(cv2.y), v3 = __int_as_float(cv3.y);
        acc.x = fmaf(v0, x0.x, acc.x); acc.y = fmaf(v0, x0.y, acc.y);
        acc.x = fmaf(v1, x1.x, acc.x); acc.y = fmaf(v1, x1.y, acc.y);
        acc.x = fmaf(v2, x2.x, acc.x); acc.y = fmaf(v2, x2.y, acc.y);
        acc.x = fmaf(v3, x3.x, acc.x); acc.y = fmaf(v3, x3.y, acc.y);
    }
    for (; i < e; ++i) {
        int2 cv = colval[i];
        float2 xv = *(const float2*)(x + (size_t)cv.x * DIM + lane2);
        float v = __int_as_float(cv.y);
        acc.x = fmaf(v, xv.x, acc.x); acc.y = fmaf(v, xv.y, acc.y);
    }
    return acc;
}

__global__ __launch_bounds__(256) void spmm_pull2(
    const int* __restrict__ rpA, const int2* __restrict__ cvA,
    const float* __restrict__ xA, float* __restrict__ yA,
    const int* __restrict__ rpB, const int2* __restrict__ cvB,
    const float* __restrict__ xB, float* __restrict__ yB)
{
    int half = gridDim.x >> 1;
    bool second = (int)blockIdx.x >= half;
    int blk = second ? (blockIdx.x - half) : blockIdx.x;
    int row = blk * 4 + (threadIdx.x >> 6);
    if (row >= N_NODES) return;
    int lane2 = (threadIdx.x & 63) * 2;
    const int* rp = second ? rpB : rpA;
    const int2* cv = second ? cvB : cvA;
    const float* x = second ? xB : xA;
    float* y = second ? yB : yA;
    float2 acc = spmm_row(rp, cv, x, row, lane2);
    *(float2*)(y + (size_t)row * DIM + lane2) = acc;
}

// nA blocks handle set A, rest set B.  (t = M@x; p += t; q += t*z)
__global__ __launch_bounds__(256) void spmm_acc2_pair(
    const int* __restrict__ rpA, const int2* __restrict__ cvA,
    const float* __restrict__ xA, float* __restrict__ pA,
    float* __restrict__ qA, const float* __restrict__ zA,
    const int* __restrict__ rpB, const int2* __restrict__ cvB,
    const float* __restrict__ xB, float* __restrict__ pB,
    float* __restrict__ qB, const float* __restrict__ zB, int nA)
{
    bool second = (int)blockIdx.x >= nA;
    int blk = second ? (blockIdx.x - nA) : blockIdx.x;
    int row = blk * 4 + (threadIdx.x >> 6);
    if (row >= N_NODES) return;
    int lane2 = (threadIdx.x & 63) * 2;
    const int* rp = second ? rpB : rpA;
    const int2* cv = second ? cvB : cvA;
    const float* x = second ? xB : xA;
    float* p = second ? pB : pA;
    float* q = second ? qB : qA;
    const float* z = second ? zB : zA;
    float2 acc = spmm_row(rp, cv, x, row, lane2);
    size_t off = (size_t)row * DIM + lane2;
    float2 pv = *(float2*)(p + off);
    float2 qv = *(float2*)(q + off);
    float2 zv = *(const float2*)(z + off);
    pv.x += acc.x; pv.y += acc.y;
    qv.x += acc.x * zv.x; qv.y += acc.y * zv.y;
    *(float2*)(p + off) = pv;
    *(float2*)(q + off) = qv;
}

// ===========================================================================
// Elementwise fusions
// ===========================================================================
__device__ __forceinline__ float4 f4mul(float4 a, float4 b) {
    return make_float4(a.x*b.x, a.y*b.y, a.z*b.z, a.w*b.w);
}
__device__ __forceinline__ float4 f4add(float4 a, float4 b) {
    return make_float4(a.x+b.x, a.y+b.y, a.z+b.z, a.w+b.w);
}

__global__ __launch_bounds__(256) void ew_hop0_kernel(
    const float4* __restrict__ a, const float4* __restrict__ b,
    const float4* __restrict__ xl, const float4* __restrict__ xr,
    float4* __restrict__ sml, float4* __restrict__ smr,
    float4* __restrict__ kl, float4* __restrict__ kr, int n4)
{
    int i = blockIdx.x * 256 + threadIdx.x;
    if (i >= n4) return;
    float4 av = a[i], bv = b[i], lv = xl[i], rv = xr[i];
    float4 ml = f4mul(av, lv);
    float4 mr = f4mul(bv, rv);
    sml[i] = ml; smr[i] = mr;
    kl[i] = f4add(av, ml);
    kr[i] = f4add(bv, mr);
}

__global__ __launch_bounds__(256) void ew_b0_kernel(
    const float4* __restrict__ a, const float4* b,
    const float4* __restrict__ y1, const float4* __restrict__ z1,
    float4* __restrict__ sm, float4* __restrict__ kl,
    float4* krb, int n4)
{
    int i = blockIdx.x * 256 + threadIdx.x;
    if (i >= n4) return;
    float4 av = a[i], bv = b[i], yv = y1[i], zv = z1[i];
    float4 ml = f4mul(av, yv);
    sm[i] = ml;
    kl[i] = f4add(av, ml);
    krb[i] = f4add(bv, f4mul(bv, zv));
}

// ===========================================================================
// MFMA double GEMM: out = relu( X1@W1^T + X2@W2^T + 2*(b1+b2) ), bf16 via LDS
// ===========================================================================
__global__ __launch_bounds__(256) void gemm2_mfma(
    const float* __restrict__ X1A, const float* __restrict__ X2A,
    float* __restrict__ outA,
    const float* __restrict__ X1B, const float* __restrict__ X2B,
    float* __restrict__ outB,
    const float* __restrict__ W1, const float* __restrict__ W2,
    const float* __restrict__ b1, const float* __restrict__ b2)
{
    __shared__ unsigned short xs[2][64 * DIM];   // swizzled bf16, 32 KB

    const int nblkA = N_NODES / 64;
    bool second = (int)blockIdx.x >= nblkA;
    int blk = second ? (blockIdx.x - nblkA) : blockIdx.x;
    const float* X1 = second ? X1B : X1A;
    const float* X2 = second ? X2B : X2A;
    float* out = second ? outB : outA;

    const int row0 = blk * 64;
    const int tid = threadIdx.x;

    #pragma unroll
    for (int it = 0; it < 4; ++it) {
        int id = tid + 256 * it;          // 0..1023
        int r = id >> 4;                  // 0..63
        int c16 = id & 15;                // 16B chunk = 8 floats
        int byte = (c16 * 16) ^ ((r & 7) << 4);
        const float4* g1 = (const float4*)(X1 + (size_t)(row0 + r) * DIM + c16 * 8);
        const float4* g2 = (const float4*)(X2 + (size_t)(row0 + r) * DIM + c16 * 8);
        *(short8*)((char*)&xs[0][r * DIM] + byte) = pack_bf8(g1[0], g1[1]);
        *(short8*)((char*)&xs[1][r * DIM] + byte) = pack_bf8(g2[0], g2[1]);
    }

    const int wv = tid >> 6;
    const int lane = tid & 63;
    const int lr = lane & 15;
    const int kgrp = lane >> 4;
    const int colbase = wv * 32;

    short8 wf[2][2][4];
    #pragma unroll
    for (int mat = 0; mat < 2; ++mat) {
        const float* W = mat ? W2 : W1;
        #pragma unroll
        for (int nt = 0; nt < 2; ++nt) {
            #pragma unroll
            for (int ks = 0; ks < 4; ++ks) {
                const float* wp = W + (size_t)(colbase + nt * 16 + lr) * DIM
                                    + ks * 32 + kgrp * 8;
                wf[mat][nt][ks] = pack_bf8(*(const float4*)wp, *(const float4*)(wp + 4));
            }
        }
    }

    __syncthreads();

    f32x4 acc[4][2];
    #pragma unroll
    for (int mt = 0; mt < 4; ++mt)
        #pragma unroll
        for (int nt = 0; nt < 2; ++nt)
            acc[mt][nt] = (f32x4){0.f, 0.f, 0.f, 0.f};

    #pragma unroll
    for (int ks = 0; ks < 4; ++ks) {
        short8 a1f[4], a2f[4];
        #pragma unroll
        for (int mt = 0; mt < 4; ++mt) {
            int row = mt * 16 + lr;
            int kbyte = ks * 64 + kgrp * 16;
            int byte = row * 256 + (kbyte ^ ((row & 7) << 4));
            a1f[mt] = *(const short8*)((const char*)&xs[0][0] + byte);
            a2f[mt] = *(const short8*)((const char*)&xs[1][0] + byte);
        }
        #pragma unroll
        for (int mt = 0; mt < 4; ++mt) {
            #pragma unroll
            for (int nt = 0; nt < 2; ++nt) {
                acc[mt][nt] = __builtin_amdgcn_mfma_f32_16x16x32_bf16(
                    a1f[mt], wf[0][nt][ks], acc[mt][nt], 0, 0, 0);
                acc[mt][nt] = __builtin_amdgcn_mfma_f32_16x16x32_bf16(
                    a2f[mt], wf[1][nt][ks], acc[mt][nt], 0, 0, 0);
            }
        }
    }

    #pragma unroll
    for (int nt = 0; nt < 2; ++nt) {
        int col = colbase + nt * 16 + lr;
        float c = 2.0f * (b1[col] + b2[col]);
        #pragma unroll
        for (int mt = 0; mt < 4; ++mt) {
            #pragma unroll
            for (int r = 0; r < 4; ++r) {
                int row = row0 + mt * 16 + kgrp * 4 + r;
                out[(size_t)row * DIM + col] = fmaxf(acc[mt][nt][r] + c, 0.f);
            }
        }
    }
}

// ===========================================================================
extern "C" void kernel_launch(void* const* d_in, const int* in_sizes, int n_in,
                              void* d_out, int out_size, void* d_ws, size_t ws_size,
                              hipStream_t stream)
{
    const float* l_feat = (const float*)d_in[0];
    const float* r_feat = (const float*)d_in[1];
    const int*   rows   = (const int*)d_in[2];
    const int*   cols   = (const int*)d_in[3];
    const float* vals   = (const float*)d_in[4];
    const float* W1a    = (const float*)d_in[5];
    const float* b1a    = (const float*)d_in[6];
    const float* W2a    = (const float*)d_in[7];
    const float* b2a    = (const float*)d_in[8];
    const float* W1b    = (const float*)d_in[9];
    const float* b1b    = (const float*)d_in[10];
    const float* W2b    = (const float*)d_in[11];
    const float* b2b    = (const float*)d_in[12];
    float* out = (float*)d_out;

    const size_t NT = (size_t)N_NODES * DIM;
    char* ws = (char*)d_ws;
    float* F0 = (float*)ws;
    float* F1 = F0 + NT;
    float* F2 = F1 + NT;
    float* F3 = F2 + NT;
    float* F4 = F3 + NT;
    float* F5 = F4 + NT;
    char* p = (char*)(F5 + NT);
    int* rowptrA = (int*)p;             p += (size_t)(N_NODES + 1) * 4;
    int* rowptrT = (int*)p;             p += (size_t)(N_NODES + 1) * 4;
    int* curA    = (int*)p;             p += (size_t)N_NODES * 4;
    int* curT    = (int*)p;             p += (size_t)N_NODES * 4;
    int2* colvalA = (int2*)p;           p += (size_t)E_EDGES * 8;
    int2* colvalT = (int2*)p;

    const int n4 = (int)(NT / 4);
    dim3 blk(256);
    dim3 ewGrid((n4 + 255) / 256);
    dim3 eGrid((E_EDGES + 255) / 256);
    const int spBlocks = (N_NODES + 3) / 4;
    const int gmBlocks = N_NODES / 64;

    // ---- build CSR for A and A^T ----
    hipMemsetAsync(curA, 0, (size_t)N_NODES * 4, stream);
    hipMemsetAsync(curT, 0, (size_t)N_NODES * 4, stream);
    hist_kernel<<<eGrid, blk, 0, stream>>>(rows, cols, curA, curT, E_EDGES);
    scan_kernel<<<1, 1024, 0, stream>>>(curA, rowptrA, N_NODES);
    scan_kernel<<<1, 1024, 0, stream>>>(curT, rowptrT, N_NODES);
    hipMemcpyAsync(curA, rowptrA, (size_t)N_NODES * 4, hipMemcpyDeviceToDevice, stream);
    hipMemcpyAsync(curT, rowptrT, (size_t)N_NODES * 4, hipMemcpyDeviceToDevice, stream);
    scatter_kernel<<<eGrid, blk, 0, stream>>>(rows, cols, vals, curA, curT,
                                              colvalA, colvalT, E_EDGES);

    // ======================= Layer A =======================
    spmm_pull2<<<dim3(2 * spBlocks), blk, 0, stream>>>(
        rowptrA, colvalA, r_feat, F0,
        rowptrT, colvalT, l_feat, F1);
    ew_hop0_kernel<<<ewGrid, blk, 0, stream>>>(
        (const float4*)F0, (const float4*)F1,
        (const float4*)l_feat, (const float4*)r_feat,
        (float4*)F2, (float4*)F3, (float4*)F4, (float4*)F5, n4);
    spmm_acc2_pair<<<dim3(2 * spBlocks), blk, 0, stream>>>(
        rowptrA, colvalA, F5, F0, F2, F4,
        rowptrT, colvalT, F4, F1, F3, F5, spBlocks);
    gemm2_mfma<<<dim3(2 * gmBlocks), blk, 0, stream>>>(
        F0, F2, F4, F1, F3, F5, W1a, W2a, b1a, b2a);   // y1->F4, z1->F5

    // ======================= Layer B (l-output only) =======================
    spmm_pull2<<<dim3(2 * spBlocks), blk, 0, stream>>>(
        rowptrA, colvalA, F5, F2,
        rowptrT, colvalT, F4, F3);
    ew_b0_kernel<<<ewGrid, blk, 0, stream>>>(
        (const float4*)F2, (const float4*)F3,
        (const float4*)F4, (const float4*)F5,
        (float4*)F0, (float4*)F1, (float4*)F3, n4);
    spmm_acc2_pair<<<dim3(spBlocks), blk, 0, stream>>>(
        rowptrA, colvalA, F3, F2, F0, F1,
        rowptrA, colvalA, F3, F2, F0, F1, spBlocks);   // only set A runs
    gemm2_mfma<<<dim3(gmBlocks), blk, 0, stream>>>(
        F2, F0, out, F2, F0, out, W1b, W2b, b1b, b2b); // only set A runs
}

// Round 4
// 473.562 us; speedup vs baseline: 16.7346x; 1.4190x over previous
//
#include <hip/hip_runtime.h>

#define N_NODES 40000
#define E_EDGES 640000
#define DIM 128
#define NB_SCAN 40          // ceil(N_NODES / 1024)

typedef __attribute__((ext_vector_type(8))) short short8;
typedef __attribute__((ext_vector_type(4))) float f32x4;

// fp32 -> bf16 round-to-nearest-even
__device__ __forceinline__ unsigned short f2bf(float f) {
    unsigned int u = __float_as_uint(f);
    u = u + 0x7FFFu + ((u >> 16) & 1u);
    return (unsigned short)(u >> 16);
}
__device__ __forceinline__ unsigned int pack2bf(float lo, float hi) {
    return (unsigned int)f2bf(lo) | ((unsigned int)f2bf(hi) << 16);
}
__device__ __forceinline__ float2 unpack2bf(unsigned int u) {
    return make_float2(__uint_as_float(u << 16), __uint_as_float(u & 0xFFFF0000u));
}
__device__ __forceinline__ short8 pack_bf8(float4 a, float4 b) {
    short8 r;
    r[0] = (short)f2bf(a.x); r[1] = (short)f2bf(a.y);
    r[2] = (short)f2bf(a.z); r[3] = (short)f2bf(a.w);
    r[4] = (short)f2bf(b.x); r[5] = (short)f2bf(b.y);
    r[6] = (short)f2bf(b.z); r[7] = (short)f2bf(b.w);
    return r;
}

// ===========================================================================
// CSR build
// ===========================================================================
__global__ __launch_bounds__(256) void hist_kernel(
    const int* __restrict__ rows, const int* __restrict__ cols,
    int* __restrict__ cntA, int* __restrict__ cntT, int E)
{
    int e = blockIdx.x * 256 + threadIdx.x;
    if (e >= E) return;
    atomicAdd(&cntA[rows[e]], 1);
    atomicAdd(&cntT[cols[e]], 1);
}

// fp32 -> bf16 feature conversion (l_feat, r_feat)
__global__ __launch_bounds__(256) void convert_kernel(
    const float4* __restrict__ lf, const float4* __restrict__ rf,
    uint2* __restrict__ l16, uint2* __restrict__ r16, int n4)
{
    int i = blockIdx.x * 256 + threadIdx.x;
    if (i >= n4) return;
    float4 a = lf[i];
    float4 b = rf[i];
    l16[i] = make_uint2(pack2bf(a.x, a.y), pack2bf(a.z, a.w));
    r16[i] = make_uint2(pack2bf(b.x, b.y), pack2bf(b.z, b.w));
}

// pass 1: per-1024-chunk sums of both count arrays. grid = 2*NB_SCAN
__global__ __launch_bounds__(256) void blocksum_kernel(
    const int* __restrict__ cA, const int* __restrict__ cT, int* __restrict__ bs)
{
    int arr = blockIdx.x / NB_SCAN;
    int b = blockIdx.x % NB_SCAN;
    const int* c = arr ? cT : cA;
    int base = b * 1024 + threadIdx.x * 4;
    int s = 0;
    #pragma unroll
    for (int k = 0; k < 4; ++k) {
        int i = base + k;
        if (i < N_NODES) s += c[i];
    }
    #pragma unroll
    for (int off = 1; off < 64; off <<= 1) s += __shfl_xor(s, off, 64);
    __shared__ int ws[4];
    int lane = threadIdx.x & 63, wid = threadIdx.x >> 6;
    if (lane == 0) ws[wid] = s;
    __syncthreads();
    if (threadIdx.x == 0) bs[arr * NB_SCAN + b] = ws[0] + ws[1] + ws[2] + ws[3];
}

// pass 2: exclusive scan of the NB_SCAN block sums for both arrays (in place)
__global__ __launch_bounds__(128) void scan_bsums(int* __restrict__ bs)
{
    int arr = threadIdx.x >> 6;
    int lane = threadIdx.x & 63;
    int v = (lane < NB_SCAN) ? bs[arr * NB_SCAN + lane] : 0;
    int incl = v;
    #pragma unroll
    for (int off = 1; off < 64; off <<= 1) {
        int t = __shfl_up(incl, off, 64);
        if (lane >= off) incl += t;
    }
    if (lane < NB_SCAN) bs[arr * NB_SCAN + lane] = incl - v;
}

// pass 3: full exclusive scan -> rowptr (and cursor copy). grid = 2*NB_SCAN
__global__ __launch_bounds__(256) void scan_finalize(
    const int* __restrict__ cA, const int* __restrict__ cT,
    const int* __restrict__ bs,
    int* __restrict__ rpA, int* __restrict__ rpT,
    int* __restrict__ curA, int* __restrict__ curT)
{
    int arr = blockIdx.x / NB_SCAN;
    int b = blockIdx.x % NB_SCAN;
    const int* c = arr ? cT : cA;
    int* rp = arr ? rpT : rpA;
    int* cur = arr ? curT : curA;
    int tid = threadIdx.x, lane = tid & 63, wid = tid >> 6;
    int base = b * 1024 + tid * 4;
    int cv[4], lp[4];
    #pragma unroll
    for (int k = 0; k < 4; ++k) cv[k] = (base + k < N_NODES) ? c[base + k] : 0;
    lp[0] = 0; lp[1] = cv[0]; lp[2] = lp[1] + cv[1]; lp[3] = lp[2] + cv[2];
    int ts = lp[3] + cv[3];
    int incl = ts;
    #pragma unroll
    for (int off = 1; off < 64; off <<= 1) {
        int t = __shfl_up(incl, off, 64);
        if (lane >= off) incl += t;
    }
    int texcl = incl - ts;
    __shared__ int wsum[4];
    if (lane == 63) wsum[wid] = incl;
    __syncthreads();
    int woff = 0;
    #pragma unroll
    for (int w = 0; w < 4; ++w) if (w < wid) woff += wsum[w];
    int off0 = bs[arr * NB_SCAN + b] + woff + texcl;
    #pragma unroll
    for (int k = 0; k < 4; ++k) {
        int i = base + k;
        if (i < N_NODES) {
            int o = off0 + lp[k];
            rp[i] = o;
            cur[i] = o;
            if (i == N_NODES - 1) rp[N_NODES] = o + cv[k];
        }
    }
}

__global__ __launch_bounds__(256) void scatter_kernel(
    const int* __restrict__ rows, const int* __restrict__ cols,
    const float* __restrict__ vals,
    int* __restrict__ curA, int* __restrict__ curT,
    int2* __restrict__ colvalA, int2* __restrict__ colvalT, int E)
{
    int e = blockIdx.x * 256 + threadIdx.x;
    if (e >= E) return;
    int r = rows[e], c = cols[e];
    int v = __float_as_int(vals[e]);
    int pA = atomicAdd(&curA[r], 1);
    colvalA[pA] = make_int2(c, v);
    int pT = atomicAdd(&curT[c], 1);
    colvalT[pT] = make_int2(r, v);
}

// ===========================================================================
// bf16 pull-gather row body (unroll 4): acc = sum_e v_e * x16[col_e][lane]
// ===========================================================================
__device__ __forceinline__ float2 gather_bf16(
    const int* __restrict__ rp, const int2* __restrict__ cv,
    const unsigned int* __restrict__ x, int row, int lane)
{
    int s = rp[row], e = rp[row + 1];
    float2 acc = make_float2(0.f, 0.f);
    int i = s;
    for (; i + 4 <= e; i += 4) {
        int2 c0 = cv[i], c1 = cv[i+1], c2 = cv[i+2], c3 = cv[i+3];
        unsigned int u0 = x[c0.x * 64 + lane];
        unsigned int u1 = x[c1.x * 64 + lane];
        unsigned int u2 = x[c2.x * 64 + lane];
        unsigned int u3 = x[c3.x * 64 + lane];
        float v0 = __int_as_float(c0.y), v1 = __int_as_float(c1.y);
        float v2 = __int_as_float(c2.y), v3 = __int_as_float(c3.y);
        float2 f0 = unpack2bf(u0), f1 = unpack2bf(u1);
        float2 f2 = unpack2bf(u2), f3 = unpack2bf(u3);
        acc.x = fmaf(v0, f0.x, acc.x); acc.y = fmaf(v0, f0.y, acc.y);
        acc.x = fmaf(v1, f1.x, acc.x); acc.y = fmaf(v1, f1.y, acc.y);
        acc.x = fmaf(v2, f2.x, acc.x); acc.y = fmaf(v2, f2.y, acc.y);
        acc.x = fmaf(v3, f3.x, acc.x); acc.y = fmaf(v3, f3.y, acc.y);
    }
    for (; i < e; ++i) {
        int2 cc = cv[i];
        unsigned int u = x[cc.x * 64 + lane];
        float v = __int_as_float(cc.y);
        float2 f = unpack2bf(u);
        acc.x = fmaf(v, f.x, acc.x); acc.y = fmaf(v, f.y, acc.y);
    }
    return acc;
}

// ===========================================================================
// Layer A hop0 fused: a = A@r16, b = AT@l16; write Sa=a, Sb=b, SmL=a*l,
// SmR=b*r (fp32) and Kl=a+a*l, Kr=b+b*r (bf16)
// ===========================================================================
__global__ __launch_bounds__(256) void spmm_hop0(
    const int* __restrict__ rpA, const int2* __restrict__ cvA,
    const int* __restrict__ rpT, const int2* __restrict__ cvT,
    const unsigned int* __restrict__ r16, const unsigned int* __restrict__ l16,
    const float* __restrict__ lf, const float* __restrict__ rf,
    float* __restrict__ Fa, float* __restrict__ Fb,
    float* __restrict__ FmL, float* __restrict__ FmR,
    unsigned int* __restrict__ Kl16, unsigned int* __restrict__ Kr16)
{
    int row = blockIdx.x * 4 + (threadIdx.x >> 6);
    if (row >= N_NODES) return;
    int lane = threadIdx.x & 63;
    float2 a = gather_bf16(rpA, cvA, r16, row, lane);
    float2 b = gather_bf16(rpT, cvT, l16, row, lane);
    size_t off = (size_t)row * DIM + lane * 2;
    float2 lv = *(const float2*)(lf + off);
    float2 rv = *(const float2*)(rf + off);
    float2 ml = make_float2(a.x * lv.x, a.y * lv.y);
    float2 mr = make_float2(b.x * rv.x, b.y * rv.y);
    *(float2*)(Fa + off) = a;
    *(float2*)(Fb + off) = b;
    *(float2*)(FmL + off) = ml;
    *(float2*)(FmR + off) = mr;
    Kl16[row * 64 + lane] = pack2bf(a.x + ml.x, a.y + ml.y);
    Kr16[row * 64 + lane] = pack2bf(b.x + mr.x, b.y + mr.y);
}

// t = M@x16 ; p += t ; q += t * unpack(z16).  Two sets: blocks >= nA -> set B.
__global__ __launch_bounds__(256) void spmm_acc2_pair(
    const int* __restrict__ rpA, const int2* __restrict__ cvA,
    const unsigned int* __restrict__ xA, float* __restrict__ pA,
    float* __restrict__ qA, const unsigned int* __restrict__ zA,
    const int* __restrict__ rpB, const int2* __restrict__ cvB,
    const unsigned int* __restrict__ xB, float* __restrict__ pB,
    float* __restrict__ qB, const unsigned int* __restrict__ zB, int nA)
{
    bool second = (int)blockIdx.x >= nA;
    int blk = second ? (blockIdx.x - nA) : blockIdx.x;
    int row = blk * 4 + (threadIdx.x >> 6);
    if (row >= N_NODES) return;
    int lane = threadIdx.x & 63;
    const int* rp = second ? rpB : rpA;
    const int2* cv = second ? cvB : cvA;
    const unsigned int* x = second ? xB : xA;
    float* p = second ? pB : pA;
    float* q = second ? qB : qA;
    const unsigned int* z = second ? zB : zA;
    float2 acc = gather_bf16(rp, cv, x, row, lane);
    size_t off = (size_t)row * DIM + lane * 2;
    float2 pv = *(float2*)(p + off);
    float2 qv = *(float2*)(q + off);
    float2 zv = unpack2bf(z[row * 64 + lane]);
    pv.x += acc.x; pv.y += acc.y;
    qv.x += acc.x * zv.x; qv.y += acc.y * zv.y;
    *(float2*)(p + off) = pv;
    *(float2*)(q + off) = qv;
}

// Layer B hop0 fused: a = A@z16, b = AT@y16; Sa=a, Sm=a*y; Klb16=a+a*y;
// Krb16 = b + b*z
__global__ __launch_bounds__(256) void spmm_b0(
    const int* __restrict__ rpA, const int2* __restrict__ cvA,
    const int* __restrict__ rpT, const int2* __restrict__ cvT,
    const unsigned int* __restrict__ z16, const unsigned int* __restrict__ y16,
    float* __restrict__ Fsa, float* __restrict__ Fsm,
    unsigned int* __restrict__ Klb16, unsigned int* __restrict__ Krb16)
{
    int row = blockIdx.x * 4 + (threadIdx.x >> 6);
    if (row >= N_NODES) return;
    int lane = threadIdx.x & 63;
    float2 a = gather_bf16(rpA, cvA, z16, row, lane);
    float2 b = gather_bf16(rpT, cvT, y16, row, lane);
    float2 yv = unpack2bf(y16[row * 64 + lane]);
    float2 zv = unpack2bf(z16[row * 64 + lane]);
    float2 ml = make_float2(a.x * yv.x, a.y * yv.y);
    size_t off = (size_t)row * DIM + lane * 2;
    *(float2*)(Fsa + off) = a;
    *(float2*)(Fsm + off) = ml;
    Klb16[row * 64 + lane] = pack2bf(a.x + ml.x, a.y + ml.y);
    Krb16[row * 64 + lane] = pack2bf(b.x + b.x * zv.x, b.y + b.y * zv.y);
}

// ===========================================================================
// MFMA double GEMM: res = relu( X1@W1^T + X2@W2^T + 2*(b1+b2) )
// Stores fp32 (if outf) and/or bf16 (if out16). Two sets via blockIdx split.
// ===========================================================================
__global__ __launch_bounds__(256) void gemm2_mfma(
    const float* __restrict__ X1A, const float* __restrict__ X2A,
    float* outfA, unsigned short* out16A,
    const float* __restrict__ X1B, const float* __restrict__ X2B,
    float* outfB, unsigned short* out16B,
    const float* __restrict__ W1, const float* __restrict__ W2,
    const float* __restrict__ b1, const float* __restrict__ b2)
{
    __shared__ unsigned short xs[2][64 * DIM];   // swizzled bf16, 32 KB

    const int nblkA = N_NODES / 64;
    bool second = (int)blockIdx.x >= nblkA;
    int blk = second ? (blockIdx.x - nblkA) : blockIdx.x;
    const float* X1 = second ? X1B : X1A;
    const float* X2 = second ? X2B : X2A;
    float* outf = second ? outfB : outfA;
    unsigned short* out16 = second ? out16B : out16A;

    const int row0 = blk * 64;
    const int tid = threadIdx.x;

    #pragma unroll
    for (int it = 0; it < 4; ++it) {
        int id = tid + 256 * it;          // 0..1023
        int r = id >> 4;                  // 0..63
        int c16 = id & 15;                // 16B chunk = 8 floats
        int byte = (c16 * 16) ^ ((r & 7) << 4);
        const float4* g1 = (const float4*)(X1 + (size_t)(row0 + r) * DIM + c16 * 8);
        const float4* g2 = (const float4*)(X2 + (size_t)(row0 + r) * DIM + c16 * 8);
        *(short8*)((char*)&xs[0][r * DIM] + byte) = pack_bf8(g1[0], g1[1]);
        *(short8*)((char*)&xs[1][r * DIM] + byte) = pack_bf8(g2[0], g2[1]);
    }

    const int wv = tid >> 6;
    const int lane = tid & 63;
    const int lr = lane & 15;
    const int kgrp = lane >> 4;
    const int colbase = wv * 32;

    short8 wf[2][2][4];
    #pragma unroll
    for (int mat = 0; mat < 2; ++mat) {
        const float* W = mat ? W2 : W1;
        #pragma unroll
        for (int nt = 0; nt < 2; ++nt) {
            #pragma unroll
            for (int ks = 0; ks < 4; ++ks) {
                const float* wp = W + (size_t)(colbase + nt * 16 + lr) * DIM
                                    + ks * 32 + kgrp * 8;
                wf[mat][nt][ks] = pack_bf8(*(const float4*)wp, *(const float4*)(wp + 4));
            }
        }
    }

    __syncthreads();

    f32x4 acc[4][2];
    #pragma unroll
    for (int mt = 0; mt < 4; ++mt)
        #pragma unroll
        for (int nt = 0; nt < 2; ++nt)
            acc[mt][nt] = (f32x4){0.f, 0.f, 0.f, 0.f};

    #pragma unroll
    for (int ks = 0; ks < 4; ++ks) {
        short8 a1f[4], a2f[4];
        #pragma unroll
        for (int mt = 0; mt < 4; ++mt) {
            int row = mt * 16 + lr;
            int kbyte = ks * 64 + kgrp * 16;
            int byte = row * 256 + (kbyte ^ ((row & 7) << 4));
            a1f[mt] = *(const short8*)((const char*)&xs[0][0] + byte);
            a2f[mt] = *(const short8*)((const char*)&xs[1][0] + byte);
        }
        #pragma unroll
        for (int mt = 0; mt < 4; ++mt) {
            #pragma unroll
            for (int nt = 0; nt < 2; ++nt) {
                acc[mt][nt] = __builtin_amdgcn_mfma_f32_16x16x32_bf16(
                    a1f[mt], wf[0][nt][ks], acc[mt][nt], 0, 0, 0);
                acc[mt][nt] = __builtin_amdgcn_mfma_f32_16x16x32_bf16(
                    a2f[mt], wf[1][nt][ks], acc[mt][nt], 0, 0, 0);
            }
        }
    }

    bool hasf = outf != nullptr;
    bool has16 = out16 != nullptr;
    #pragma unroll
    for (int nt = 0; nt < 2; ++nt) {
        int col = colbase + nt * 16 + lr;
        float c = 2.0f * (b1[col] + b2[col]);
        #pragma unroll
        for (int mt = 0; mt < 4; ++mt) {
            #pragma unroll
            for (int r = 0; r < 4; ++r) {
                int row = row0 + mt * 16 + kgrp * 4 + r;
                float o = fmaxf(acc[mt][nt][r] + c, 0.f);
                if (hasf) outf[(size_t)row * DIM + col] = o;
                if (has16) out16[(size_t)row * DIM + col] = f2bf(o);
            }
        }
    }
}

// ===========================================================================
extern "C" void kernel_launch(void* const* d_in, const int* in_sizes, int n_in,
                              void* d_out, int out_size, void* d_ws, size_t ws_size,
                              hipStream_t stream)
{
    const float* l_feat = (const float*)d_in[0];
    const float* r_feat = (const float*)d_in[1];
    const int*   rows   = (const int*)d_in[2];
    const int*   cols   = (const int*)d_in[3];
    const float* vals   = (const float*)d_in[4];
    const float* W1a    = (const float*)d_in[5];
    const float* b1a    = (const float*)d_in[6];
    const float* W2a    = (const float*)d_in[7];
    const float* b2a    = (const float*)d_in[8];
    const float* W1b    = (const float*)d_in[9];
    const float* b1b    = (const float*)d_in[10];
    const float* W2b    = (const float*)d_in[11];
    const float* b2b    = (const float*)d_in[12];
    float* out = (float*)d_out;

    const size_t NT = (size_t)N_NODES * DIM;
    char* ws = (char*)d_ws;
    float* F0 = (float*)ws;             // Sa(L) / layerB Sm
    float* F1 = F0 + NT;                // Sb(R) / layerB Sa
    float* F2 = F1 + NT;                // SmL
    float* F3 = F2 + NT;                // SmR
    char* p = (char*)(F3 + NT);
    unsigned int* l16  = (unsigned int*)p;  p += NT * 2;   // l_feat bf16 -> y1 bf16
    unsigned int* r16  = (unsigned int*)p;  p += NT * 2;   // r_feat bf16 -> z1 bf16
    unsigned int* Kl16 = (unsigned int*)p;  p += NT * 2;   // Kl1 -> Klb
    unsigned int* Kr16 = (unsigned int*)p;  p += NT * 2;   // Kr1 -> Krb
    int* rowptrA = (int*)p;             p += (size_t)(N_NODES + 1) * 4;
    int* rowptrT = (int*)p;             p += (size_t)(N_NODES + 1) * 4;
    int* curA    = (int*)p;             p += (size_t)N_NODES * 4;
    int* curT    = (int*)p;             p += (size_t)N_NODES * 4;
    int* bsums   = (int*)p;             p += (size_t)(2 * NB_SCAN) * 4;
    int2* colvalA = (int2*)p;           p += (size_t)E_EDGES * 8;
    int2* colvalT = (int2*)p;

    const int n4 = (int)(NT / 4);
    dim3 blk(256);
    dim3 cvGrid((n4 + 255) / 256);
    dim3 eGrid((E_EDGES + 255) / 256);
    const int spBlocks = (N_NODES + 3) / 4;
    const int gmBlocks = N_NODES / 64;

    // ---- CSR build (A and A^T) + bf16 feature conversion ----
    hipMemsetAsync(curA, 0, (size_t)N_NODES * 4, stream);
    hipMemsetAsync(curT, 0, (size_t)N_NODES * 4, stream);
    hist_kernel<<<eGrid, blk, 0, stream>>>(rows, cols, curA, curT, E_EDGES);
    convert_kernel<<<cvGrid, blk, 0, stream>>>(
        (const float4*)l_feat, (const float4*)r_feat,
        (uint2*)l16, (uint2*)r16, n4);
    blocksum_kernel<<<dim3(2 * NB_SCAN), blk, 0, stream>>>(curA, curT, bsums);
    scan_bsums<<<1, 128, 0, stream>>>(bsums);
    scan_finalize<<<dim3(2 * NB_SCAN), blk, 0, stream>>>(
        curA, curT, bsums, rowptrA, rowptrT, curA, curT);
    scatter_kernel<<<eGrid, blk, 0, stream>>>(rows, cols, vals, curA, curT,
                                              colvalA, colvalT, E_EDGES);

    // ======================= Layer A =======================
    // a=A@r16, b=AT@l16; F0=a, F1=b, F2=a*l, F3=b*r; Kl16, Kr16
    spmm_hop0<<<dim3(spBlocks), blk, 0, stream>>>(
        rowptrA, colvalA, rowptrT, colvalT, r16, l16, l_feat, r_feat,
        F0, F1, F2, F3, Kl16, Kr16);
    // t=A@Kr1: F0+=t, F2+=t*Kl1 ; t=AT@Kl1: F1+=t, F3+=t*Kr1
    spmm_acc2_pair<<<dim3(2 * spBlocks), blk, 0, stream>>>(
        rowptrA, colvalA, Kr16, F0, F2, Kl16,
        rowptrT, colvalT, Kl16, F1, F3, Kr16, spBlocks);
    // y1 (bf16) -> l16 ; z1 (bf16) -> r16
    gemm2_mfma<<<dim3(2 * gmBlocks), blk, 0, stream>>>(
        F0, F2, nullptr, (unsigned short*)l16,
        F1, F3, nullptr, (unsigned short*)r16,
        W1a, W2a, b1a, b2a);

    // ======================= Layer B (l-output only) =======================
    // a=A@z1, b=AT@y1; F1=a (Sa), F0=a*y1 (Sm); Klb->Kl16, Krb->Kr16
    spmm_b0<<<dim3(spBlocks), blk, 0, stream>>>(
        rowptrA, colvalA, rowptrT, colvalT, r16, l16,
        F1, F0, Kl16, Kr16);
    // t=A@Krb: F1+=t, F0+=t*Klb
    spmm_acc2_pair<<<dim3(spBlocks), blk, 0, stream>>>(
        rowptrA, colvalA, Kr16, F1, F0, Kl16,
        rowptrA, colvalA, Kr16, F1, F0, Kl16, spBlocks);
    // out = relu(F1@W1b^T + F0@W2b^T + 2(b1b+b2b))
    gemm2_mfma<<<dim3(gmBlocks), blk, 0, stream>>>(
        F1, F0, out, nullptr,
        F1, F0, out, nullptr,
        W1b, W2b, b1b, b2b);
}

// Round 5
// 431.223 us; speedup vs baseline: 18.3777x; 1.0982x over previous
//
#include <hip/hip_runtime.h>

#define N_NODES 40000
#define E_EDGES 640000
#define DIM 128
#define NBKT 157            // buckets of 256 rows: 157*256 = 40192 >= 40000
#define BKT_CAP 6144        // mean 4096/bucket, std ~64 -> +32 sigma headroom

typedef __attribute__((ext_vector_type(8))) short short8;
typedef __attribute__((ext_vector_type(4))) float f32x4;

// fp32 -> bf16 round-to-nearest-even
__device__ __forceinline__ unsigned short f2bf(float f) {
    unsigned int u = __float_as_uint(f);
    u = u + 0x7FFFu + ((u >> 16) & 1u);
    return (unsigned short)(u >> 16);
}
__device__ __forceinline__ unsigned int pack2bf(float lo, float hi) {
    return (unsigned int)f2bf(lo) | ((unsigned int)f2bf(hi) << 16);
}
__device__ __forceinline__ float2 unpack2bf(unsigned int u) {
    return make_float2(__uint_as_float(u << 16), __uint_as_float(u & 0xFFFF0000u));
}

// ===========================================================================
// fp32 -> bf16 feature conversion
// ===========================================================================
__global__ __launch_bounds__(256) void convert_kernel(
    const float4* __restrict__ lf, const float4* __restrict__ rf,
    uint2* __restrict__ l16, uint2* __restrict__ r16, int n4)
{
    int i = blockIdx.x * 256 + threadIdx.x;
    if (i >= n4) return;
    float4 a = lf[i];
    float4 b = rf[i];
    l16[i] = make_uint2(pack2bf(a.x, a.y), pack2bf(a.z, a.w));
    r16[i] = make_uint2(pack2bf(b.x, b.y), pack2bf(b.z, b.w));
}

// ===========================================================================
// CSR build phase 1: LDS-aggregated bucket partition (both directions).
// Staged record: (key<<16)|payload, val_bits. key = CSR row of that direction.
// ===========================================================================
__global__ __launch_bounds__(256) void build_p1(
    const int* __restrict__ rows, const int* __restrict__ cols,
    const float* __restrict__ vals,
    int* __restrict__ bktCnt,                    // [2*NBKT], zeroed
    uint2* __restrict__ stagedA, uint2* __restrict__ stagedT)
{
    __shared__ int cA[NBKT], cT[NBKT], bA[NBKT], bT[NBKT];
    const int tid = threadIdx.x;
    for (int i = tid; i < NBKT; i += 256) { cA[i] = 0; cT[i] = 0; }
    __syncthreads();

    int r[8], c[8];
    unsigned int v[8];
    const int base = blockIdx.x * 2048 + tid;
    #pragma unroll
    for (int k = 0; k < 8; ++k) {
        int e = base + k * 256;
        bool ok = e < E_EDGES;
        r[k] = ok ? __builtin_nontemporal_load(rows + e) : -1;
        c[k] = ok ? __builtin_nontemporal_load(cols + e) : 0;
        v[k] = ok ? __float_as_uint(__builtin_nontemporal_load(vals + e)) : 0u;
        if (ok) {
            atomicAdd(&cA[r[k] >> 8], 1);
            atomicAdd(&cT[c[k] >> 8], 1);
        }
    }
    __syncthreads();
    for (int i = tid; i < NBKT; i += 256) {
        bA[i] = atomicAdd(&bktCnt[i], cA[i]);
        bT[i] = atomicAdd(&bktCnt[NBKT + i], cT[i]);
        cA[i] = 0; cT[i] = 0;
    }
    __syncthreads();
    #pragma unroll
    for (int k = 0; k < 8; ++k) {
        if (r[k] < 0) continue;
        int ba = r[k] >> 8;
        int pa = bA[ba] + atomicAdd(&cA[ba], 1);
        if (pa < BKT_CAP) {
            unsigned long long rec =
                ((unsigned long long)v[k] << 32) |
                (((unsigned)r[k] << 16) | (unsigned)c[k]);
            __builtin_nontemporal_store(rec,
                (unsigned long long*)(stagedA + (size_t)ba * BKT_CAP + pa));
        }
        int bt = c[k] >> 8;
        int pt = bT[bt] + atomicAdd(&cT[bt], 1);
        if (pt < BKT_CAP) {
            unsigned long long rec =
                ((unsigned long long)v[k] << 32) |
                (((unsigned)c[k] << 16) | (unsigned)r[k]);
            __builtin_nontemporal_store(rec,
                (unsigned long long*)(stagedT + (size_t)bt * BKT_CAP + pt));
        }
    }
}

// exclusive scan of bucket totals for both directions; also rp[N] = total
__global__ __launch_bounds__(256) void bkt_scan(
    const int* __restrict__ bktCnt, int* __restrict__ bktBase,
    int* __restrict__ rpA, int* __restrict__ rpT)
{
    __shared__ int s[2][256];
    const int tid = threadIdx.x;
    for (int d = 0; d < 2; ++d) {
        int v = (tid < NBKT) ? min(bktCnt[d * NBKT + tid], BKT_CAP) : 0;
        s[0][tid] = v;
        __syncthreads();
        int sel = 0;
        for (int off = 1; off < 256; off <<= 1) {
            int t = s[sel][tid] + ((tid >= off) ? s[sel][tid - off] : 0);
            s[sel ^ 1][tid] = t;
            sel ^= 1;
            __syncthreads();
        }
        int incl = s[sel][tid];
        if (tid < NBKT) bktBase[d * NBKT + tid] = incl - v;
        if (tid == NBKT - 1) (d ? rpT : rpA)[N_NODES] = incl;
        __syncthreads();
    }
}

// ===========================================================================
// CSR build phase 2: per-bucket — LDS row counts -> prefix scan -> rowptr,
// then LDS-cursor placement into the final (col,val) CSR arrays.
// ===========================================================================
__global__ __launch_bounds__(256) void build_p2(
    const int* __restrict__ bktCnt, const int* __restrict__ bktBase,
    const uint2* __restrict__ stagedA, const uint2* __restrict__ stagedT,
    int* __restrict__ rpA, int* __restrict__ rpT,
    int2* __restrict__ cvA, int2* __restrict__ cvT)
{
    const int tid = threadIdx.x;
    int dir = (int)blockIdx.x >= NBKT;
    int b = blockIdx.x - dir * NBKT;
    int cnt = min(bktCnt[dir * NBKT + b], BKT_CAP);
    int cbase = bktBase[dir * NBKT + b];
    const uint2* staged = (dir ? stagedT : stagedA) + (size_t)b * BKT_CAP;
    int* rp = dir ? rpT : rpA;
    int2* cv = dir ? cvT : cvA;

    __shared__ int rc[256];
    __shared__ int s[2][256];
    rc[tid] = 0;
    __syncthreads();
    for (int i = tid; i < cnt; i += 256)
        atomicAdd(&rc[(staged[i].x >> 16) & 255], 1);
    __syncthreads();
    int own = rc[tid];
    s[0][tid] = own;
    __syncthreads();
    int sel = 0;
    for (int off = 1; off < 256; off <<= 1) {
        int t = s[sel][tid] + ((tid >= off) ? s[sel][tid - off] : 0);
        s[sel ^ 1][tid] = t;
        sel ^= 1;
        __syncthreads();
    }
    int ex = s[sel][tid] - own;
    int row = b * 256 + tid;
    if (row < N_NODES) rp[row] = cbase + ex;
    rc[tid] = ex;     // reuse as cursor
    __syncthreads();
    for (int i = tid; i < cnt; i += 256) {
        uint2 rec = staged[i];
        int local = (rec.x >> 16) & 255;
        int pos = cbase + atomicAdd(&rc[local], 1);
        cv[pos] = make_int2((int)(rec.x & 0xFFFFu), (int)rec.y);
    }
}

// ===========================================================================
// bf16 pull-gather row body (unroll 4, NT edge reads, cached x reads)
// ===========================================================================
__device__ __forceinline__ float2 gather_bf16(
    const int* __restrict__ rp, const int2* __restrict__ cv,
    const unsigned int* __restrict__ x, int row, int lane)
{
    int s = rp[row], e = rp[row + 1];
    float2 acc = make_float2(0.f, 0.f);
    int i = s;
    for (; i + 4 <= e; i += 4) {
        unsigned long long u0 = __builtin_nontemporal_load((const unsigned long long*)(cv + i));
        unsigned long long u1 = __builtin_nontemporal_load((const unsigned long long*)(cv + i + 1));
        unsigned long long u2 = __builtin_nontemporal_load((const unsigned long long*)(cv + i + 2));
        unsigned long long u3 = __builtin_nontemporal_load((const unsigned long long*)(cv + i + 3));
        unsigned int w0 = x[(unsigned)(u0 & 0xFFFFFFFFull) * 64u + lane];
        unsigned int w1 = x[(unsigned)(u1 & 0xFFFFFFFFull) * 64u + lane];
        unsigned int w2 = x[(unsigned)(u2 & 0xFFFFFFFFull) * 64u + lane];
        unsigned int w3 = x[(unsigned)(u3 & 0xFFFFFFFFull) * 64u + lane];
        float v0 = __uint_as_float((unsigned)(u0 >> 32));
        float v1 = __uint_as_float((unsigned)(u1 >> 32));
        float v2 = __uint_as_float((unsigned)(u2 >> 32));
        float v3 = __uint_as_float((unsigned)(u3 >> 32));
        float2 f0 = unpack2bf(w0), f1 = unpack2bf(w1);
        float2 f2 = unpack2bf(w2), f3 = unpack2bf(w3);
        acc.x = fmaf(v0, f0.x, acc.x); acc.y = fmaf(v0, f0.y, acc.y);
        acc.x = fmaf(v1, f1.x, acc.x); acc.y = fmaf(v1, f1.y, acc.y);
        acc.x = fmaf(v2, f2.x, acc.x); acc.y = fmaf(v2, f2.y, acc.y);
        acc.x = fmaf(v3, f3.x, acc.x); acc.y = fmaf(v3, f3.y, acc.y);
    }
    for (; i < e; ++i) {
        unsigned long long u = __builtin_nontemporal_load((const unsigned long long*)(cv + i));
        unsigned int w = x[(unsigned)(u & 0xFFFFFFFFull) * 64u + lane];
        float v = __uint_as_float((unsigned)(u >> 32));
        float2 f = unpack2bf(w);
        acc.x = fmaf(v, f.x, acc.x); acc.y = fmaf(v, f.y, acc.y);
    }
    return acc;
}

// hop0: a = M@g16 ; a16 = bf(a); m16 = bf(a*s); k16 = bf(a + a*s)
__global__ __launch_bounds__(256) void sp_hop0(
    const int* __restrict__ rp, const int2* __restrict__ cv,
    const unsigned int* __restrict__ g16, const unsigned int* __restrict__ s16,
    unsigned int* __restrict__ a16, unsigned int* __restrict__ m16,
    unsigned int* __restrict__ k16)
{
    int row = blockIdx.x * 4 + (threadIdx.x >> 6);
    if (row >= N_NODES) return;
    int lane = threadIdx.x & 63;
    float2 a = gather_bf16(rp, cv, g16, row, lane);
    int o = row * 64 + lane;
    float2 sv = unpack2bf(__builtin_nontemporal_load(s16 + o));
    float2 m = make_float2(a.x * sv.x, a.y * sv.y);
    __builtin_nontemporal_store(pack2bf(a.x, a.y), a16 + o);
    __builtin_nontemporal_store(pack2bf(m.x, m.y), m16 + o);
    __builtin_nontemporal_store(pack2bf(a.x + m.x, a.y + m.y), k16 + o);
}

// hop1: t = M@g16 ; a16 = bf(t); m16 = bf(t * s)
__global__ __launch_bounds__(256) void sp_hop1(
    const int* __restrict__ rp, const int2* __restrict__ cv,
    const unsigned int* __restrict__ g16, const unsigned int* __restrict__ s16,
    unsigned int* __restrict__ a16, unsigned int* __restrict__ m16)
{
    int row = blockIdx.x * 4 + (threadIdx.x >> 6);
    if (row >= N_NODES) return;
    int lane = threadIdx.x & 63;
    float2 t = gather_bf16(rp, cv, g16, row, lane);
    int o = row * 64 + lane;
    float2 sv = unpack2bf(__builtin_nontemporal_load(s16 + o));
    __builtin_nontemporal_store(pack2bf(t.x, t.y), a16 + o);
    __builtin_nontemporal_store(pack2bf(t.x * sv.x, t.y * sv.y), m16 + o);
}

// konly: b = M@g16 ; k16 = bf(b + b*s)
__global__ __launch_bounds__(256) void sp_konly(
    const int* __restrict__ rp, const int2* __restrict__ cv,
    const unsigned int* __restrict__ g16, const unsigned int* __restrict__ s16,
    unsigned int* __restrict__ k16)
{
    int row = blockIdx.x * 4 + (threadIdx.x >> 6);
    if (row >= N_NODES) return;
    int lane = threadIdx.x & 63;
    float2 b = gather_bf16(rp, cv, g16, row, lane);
    int o = row * 64 + lane;
    float2 sv = unpack2bf(__builtin_nontemporal_load(s16 + o));
    __builtin_nontemporal_store(
        pack2bf(b.x + b.x * sv.x, b.y + b.y * sv.y), k16 + o);
}

// ===========================================================================
// MFMA quad GEMM: res = relu( X0@W1^T + X1@W1^T + X2@W2^T + X3@W2^T
//                             + 2*(b1+b2) ), X already bf16 in memory.
// Two sets via blockIdx split; writes fp32 and/or bf16.
// ===========================================================================
struct G4 {
    const unsigned short* X[8];
    float* outf[2];
    unsigned short* o16[2];
};

__global__ __launch_bounds__(256) void gemm4_mfma(
    G4 g, const float* __restrict__ W1, const float* __restrict__ W2,
    const float* __restrict__ b1, const float* __restrict__ b2)
{
    __shared__ unsigned short xs[4][64 * DIM];   // swizzled bf16, 64 KB
    const int nblkA = N_NODES / 64;
    int second = (int)blockIdx.x >= nblkA;
    int blk = blockIdx.x - second * nblkA;
    const int row0 = blk * 64;
    const int tid = threadIdx.x;

    #pragma unroll
    for (int t = 0; t < 4; ++t) {
        const unsigned short* X = g.X[second * 4 + t];
        #pragma unroll
        for (int it = 0; it < 4; ++it) {
            int id = tid + 256 * it;
            int r = id >> 4, c16 = id & 15;
            int byte = (c16 * 16) ^ ((r & 7) << 4);
            uint4 d = *(const uint4*)(X + (size_t)(row0 + r) * DIM + c16 * 8);
            *(uint4*)((char*)&xs[t][r * DIM] + byte) = d;
        }
    }

    const int wv = tid >> 6;
    const int lane = tid & 63;
    const int lr = lane & 15;
    const int kgrp = lane >> 4;
    const int colbase = wv * 32;

    short8 wf[2][2][4];
    #pragma unroll
    for (int mat = 0; mat < 2; ++mat) {
        const float* W = mat ? W2 : W1;
        #pragma unroll
        for (int nt = 0; nt < 2; ++nt) {
            #pragma unroll
            for (int ks = 0; ks < 4; ++ks) {
                const float* wp = W + (size_t)(colbase + nt * 16 + lr) * DIM
                                    + ks * 32 + kgrp * 8;
                float4 wa = *(const float4*)wp;
                float4 wb = *(const float4*)(wp + 4);
                short8 r;
                r[0] = (short)f2bf(wa.x); r[1] = (short)f2bf(wa.y);
                r[2] = (short)f2bf(wa.z); r[3] = (short)f2bf(wa.w);
                r[4] = (short)f2bf(wb.x); r[5] = (short)f2bf(wb.y);
                r[6] = (short)f2bf(wb.z); r[7] = (short)f2bf(wb.w);
                wf[mat][nt][ks] = r;
            }
        }
    }

    __syncthreads();

    f32x4 acc[4][2];
    #pragma unroll
    for (int mt = 0; mt < 4; ++mt)
        #pragma unroll
        for (int nt = 0; nt < 2; ++nt)
            acc[mt][nt] = (f32x4){0.f, 0.f, 0.f, 0.f};

    #pragma unroll
    for (int ks = 0; ks < 4; ++ks) {
        #pragma unroll
        for (int xt = 0; xt < 4; ++xt) {
            const int wsel = xt >> 1;   // {a0,a1}->W1, {m0,m1}->W2
            short8 af[4];
            #pragma unroll
            for (int mt = 0; mt < 4; ++mt) {
                int row = mt * 16 + lr;
                int kbyte = ks * 64 + kgrp * 16;
                int byte = row * 256 + (kbyte ^ ((row & 7) << 4));
                af[mt] = *(const short8*)((const char*)&xs[xt][0] + byte);
            }
            #pragma unroll
            for (int mt = 0; mt < 4; ++mt)
                #pragma unroll
                for (int nt = 0; nt < 2; ++nt)
                    acc[mt][nt] = __builtin_amdgcn_mfma_f32_16x16x32_bf16(
                        af[mt], wf[wsel][nt][ks], acc[mt][nt], 0, 0, 0);
        }
    }

    float* outf = g.outf[second];
    unsigned short* o16 = g.o16[second];
    #pragma unroll
    for (int nt = 0; nt < 2; ++nt) {
        int col = colbase + nt * 16 + lr;
        float c = 2.0f * (b1[col] + b2[col]);
        #pragma unroll
        for (int mt = 0; mt < 4; ++mt) {
            #pragma unroll
            for (int r = 0; r < 4; ++r) {
                int row = row0 + mt * 16 + kgrp * 4 + r;
                float o = fmaxf(acc[mt][nt][r] + c, 0.f);
                if (outf) outf[(size_t)row * DIM + col] = o;
                if (o16) o16[(size_t)row * DIM + col] = f2bf(o);
            }
        }
    }
}

// ===========================================================================
extern "C" void kernel_launch(void* const* d_in, const int* in_sizes, int n_in,
                              void* d_out, int out_size, void* d_ws, size_t ws_size,
                              hipStream_t stream)
{
    const float* l_feat = (const float*)d_in[0];
    const float* r_feat = (const float*)d_in[1];
    const int*   rows   = (const int*)d_in[2];
    const int*   cols   = (const int*)d_in[3];
    const float* vals   = (const float*)d_in[4];
    const float* W1a    = (const float*)d_in[5];
    const float* b1a    = (const float*)d_in[6];
    const float* W2a    = (const float*)d_in[7];
    const float* b2a    = (const float*)d_in[8];
    const float* W1b    = (const float*)d_in[9];
    const float* b1b    = (const float*)d_in[10];
    const float* W2b    = (const float*)d_in[11];
    const float* b2b    = (const float*)d_in[12];
    float* out = (float*)d_out;

    const size_t NT = (size_t)N_NODES * DIM;       // 5.12M elems
    const size_t MAT16 = NT * 2;                   // bytes per bf16 matrix

    char* p = (char*)d_ws;
    auto alloc = [&](size_t bytes) {
        char* q = p; p += (bytes + 255) & ~(size_t)255; return q;
    };
    unsigned int* l16 = (unsigned int*)alloc(MAT16);   // l_feat -> y1
    unsigned int* r16 = (unsigned int*)alloc(MAT16);   // r_feat -> z1
    unsigned int* Kl  = (unsigned int*)alloc(MAT16);
    unsigned int* Kr  = (unsigned int*)alloc(MAT16);
    unsigned int* a0L = (unsigned int*)alloc(MAT16);
    unsigned int* m0L = (unsigned int*)alloc(MAT16);
    unsigned int* a1L = (unsigned int*)alloc(MAT16);
    unsigned int* m1L = (unsigned int*)alloc(MAT16);
    unsigned int* a0R = (unsigned int*)alloc(MAT16);
    unsigned int* m0R = (unsigned int*)alloc(MAT16);
    unsigned int* a1R = (unsigned int*)alloc(MAT16);
    unsigned int* m1R = (unsigned int*)alloc(MAT16);
    int* rpA = (int*)alloc((size_t)(N_NODES + 1) * 4);
    int* rpT = (int*)alloc((size_t)(N_NODES + 1) * 4);
    int* bktCnt  = (int*)alloc((size_t)(2 * NBKT) * 4);
    int* bktBase = (int*)alloc((size_t)(2 * NBKT) * 4);
    int2* cvA = (int2*)alloc((size_t)E_EDGES * 8);
    int2* cvT = (int2*)alloc((size_t)E_EDGES * 8);
    uint2* stagedA = (uint2*)alloc((size_t)NBKT * BKT_CAP * 8);
    uint2* stagedT = (uint2*)alloc((size_t)NBKT * BKT_CAP * 8);

    const int n4 = (int)(NT / 4);
    dim3 blk(256);
    dim3 cvGrid((n4 + 255) / 256);
    const int spBlocks = (N_NODES + 3) / 4;        // 10000
    const int gmBlocks = N_NODES / 64;             // 625
    const int p1Blocks = (E_EDGES + 2047) / 2048;  // 313

    // ---- CSR build + bf16 conversion ----
    hipMemsetAsync(bktCnt, 0, (size_t)(2 * NBKT) * 4, stream);
    convert_kernel<<<cvGrid, blk, 0, stream>>>(
        (const float4*)l_feat, (const float4*)r_feat,
        (uint2*)l16, (uint2*)r16, n4);
    build_p1<<<dim3(p1Blocks), blk, 0, stream>>>(
        rows, cols, vals, bktCnt, stagedA, stagedT);
    bkt_scan<<<1, blk, 0, stream>>>(bktCnt, bktBase, rpA, rpT);
    build_p2<<<dim3(2 * NBKT), blk, 0, stream>>>(
        bktCnt, bktBase, stagedA, stagedT, rpA, rpT, cvA, cvT);

    // ======================= Layer A =======================
    // a0 = A@r ; m0 = a0*l ; Kl = a0 + m0
    sp_hop0<<<dim3(spBlocks), blk, 0, stream>>>(rpA, cvA, r16, l16, a0L, m0L, Kl);
    // b0 = AT@l ; m0R = b0*r ; Kr = b0 + m0R
    sp_hop0<<<dim3(spBlocks), blk, 0, stream>>>(rpT, cvT, l16, r16, a0R, m0R, Kr);
    // a1 = A@Kr ; m1 = a1*Kl
    sp_hop1<<<dim3(spBlocks), blk, 0, stream>>>(rpA, cvA, Kr, Kl, a1L, m1L);
    // b1 = AT@Kl ; m1R = b1*Kr
    sp_hop1<<<dim3(spBlocks), blk, 0, stream>>>(rpT, cvT, Kl, Kr, a1R, m1R);
    {
        G4 g;
        g.X[0] = (const unsigned short*)a0L; g.X[1] = (const unsigned short*)a1L;
        g.X[2] = (const unsigned short*)m0L; g.X[3] = (const unsigned short*)m1L;
        g.X[4] = (const unsigned short*)a0R; g.X[5] = (const unsigned short*)a1R;
        g.X[6] = (const unsigned short*)m0R; g.X[7] = (const unsigned short*)m1R;
        g.outf[0] = nullptr; g.outf[1] = nullptr;
        g.o16[0] = (unsigned short*)l16;     // y1
        g.o16[1] = (unsigned short*)r16;     // z1
        gemm4_mfma<<<dim3(2 * gmBlocks), blk, 0, stream>>>(g, W1a, W2a, b1a, b2a);
    }

    // ======================= Layer B (l-output only) =======================
    // a = A@z1 ; m0 = a*y1 ; Klb = a + m0
    sp_hop0<<<dim3(spBlocks), blk, 0, stream>>>(rpA, cvA, r16, l16, a0L, m0L, Kl);
    // b = AT@y1 ; Krb = b + b*z1
    sp_konly<<<dim3(spBlocks), blk, 0, stream>>>(rpT, cvT, l16, r16, Kr);
    // a1 = A@Krb ; m1 = a1*Klb
    sp_hop1<<<dim3(spBlocks), blk, 0, stream>>>(rpA, cvA, Kr, Kl, a1L, m1L);
    {
        G4 g;
        g.X[0] = (const unsigned short*)a0L; g.X[1] = (const unsigned short*)a1L;
        g.X[2] = (const unsigned short*)m0L; g.X[3] = (const unsigned short*)m1L;
        g.X[4] = g.X[0]; g.X[5] = g.X[1]; g.X[6] = g.X[2]; g.X[7] = g.X[3];
        g.outf[0] = out; g.outf[1] = nullptr;
        g.o16[0] = nullptr; g.o16[1] = nullptr;
        gemm4_mfma<<<dim3(gmBlocks), blk, 0, stream>>>(g, W1b, W2b, b1b, b2b);
    }
}

// Round 6
// 337.858 us; speedup vs baseline: 23.4563x; 1.2763x over previous
//
#include <hip/hip_runtime.h>

#define N_NODES 40000
#define E_EDGES 640000
#define DIM 128
#define NBKT 157            // buckets of 256 rows
#define BKT_CAP 6144

typedef __attribute__((ext_vector_type(8))) short short8;
typedef __attribute__((ext_vector_type(4))) float f32x4;

__device__ __forceinline__ unsigned short f2bf(float f) {
    unsigned int u = __float_as_uint(f);
    u = u + 0x7FFFu + ((u >> 16) & 1u);
    return (unsigned short)(u >> 16);
}
__device__ __forceinline__ unsigned int pack2bf(float lo, float hi) {
    return (unsigned int)f2bf(lo) | ((unsigned int)f2bf(hi) << 16);
}
__device__ __forceinline__ float2 unpack2bf(unsigned int u) {
    return make_float2(__uint_as_float(u << 16), __uint_as_float(u & 0xFFFF0000u));
}
__device__ __forceinline__ short8 pack_bf8(float4 a, float4 b) {
    short8 r;
    r[0] = (short)f2bf(a.x); r[1] = (short)f2bf(a.y);
    r[2] = (short)f2bf(a.z); r[3] = (short)f2bf(a.w);
    r[4] = (short)f2bf(b.x); r[5] = (short)f2bf(b.y);
    r[6] = (short)f2bf(b.z); r[7] = (short)f2bf(b.w);
    return r;
}

// ===========================================================================
// fp32 -> bf16 feature conversion
// ===========================================================================
__global__ __launch_bounds__(256) void convert_kernel(
    const float4* __restrict__ lf, const float4* __restrict__ rf,
    uint2* __restrict__ l16, uint2* __restrict__ r16, int n4)
{
    int i = blockIdx.x * 256 + threadIdx.x;
    if (i >= n4) return;
    float4 a = lf[i];
    float4 b = rf[i];
    l16[i] = make_uint2(pack2bf(a.x, a.y), pack2bf(a.z, a.w));
    r16[i] = make_uint2(pack2bf(b.x, b.y), pack2bf(b.z, b.w));
}

// ===========================================================================
// CSR build phase 1: LDS-aggregated bucket partition (both directions)
// ===========================================================================
__global__ __launch_bounds__(256) void build_p1(
    const int* __restrict__ rows, const int* __restrict__ cols,
    const float* __restrict__ vals,
    int* __restrict__ bktCnt,
    uint2* __restrict__ stagedA, uint2* __restrict__ stagedT)
{
    __shared__ int cA[NBKT], cT[NBKT], bA[NBKT], bT[NBKT];
    const int tid = threadIdx.x;
    for (int i = tid; i < NBKT; i += 256) { cA[i] = 0; cT[i] = 0; }
    __syncthreads();

    int r[8], c[8];
    unsigned int v[8];
    const int base = blockIdx.x * 2048 + tid;
    #pragma unroll
    for (int k = 0; k < 8; ++k) {
        int e = base + k * 256;
        bool ok = e < E_EDGES;
        r[k] = ok ? __builtin_nontemporal_load(rows + e) : -1;
        c[k] = ok ? __builtin_nontemporal_load(cols + e) : 0;
        v[k] = ok ? __float_as_uint(__builtin_nontemporal_load(vals + e)) : 0u;
        if (ok) {
            atomicAdd(&cA[r[k] >> 8], 1);
            atomicAdd(&cT[c[k] >> 8], 1);
        }
    }
    __syncthreads();
    for (int i = tid; i < NBKT; i += 256) {
        bA[i] = atomicAdd(&bktCnt[i], cA[i]);
        bT[i] = atomicAdd(&bktCnt[NBKT + i], cT[i]);
        cA[i] = 0; cT[i] = 0;
    }
    __syncthreads();
    #pragma unroll
    for (int k = 0; k < 8; ++k) {
        if (r[k] < 0) continue;
        int ba = r[k] >> 8;
        int pa = bA[ba] + atomicAdd(&cA[ba], 1);
        if (pa < BKT_CAP) {
            unsigned long long rec =
                ((unsigned long long)v[k] << 32) |
                (((unsigned)r[k] << 16) | (unsigned)c[k]);
            __builtin_nontemporal_store(rec,
                (unsigned long long*)(stagedA + (size_t)ba * BKT_CAP + pa));
        }
        int bt = c[k] >> 8;
        int pt = bT[bt] + atomicAdd(&cT[bt], 1);
        if (pt < BKT_CAP) {
            unsigned long long rec =
                ((unsigned long long)v[k] << 32) |
                (((unsigned)c[k] << 16) | (unsigned)r[k]);
            __builtin_nontemporal_store(rec,
                (unsigned long long*)(stagedT + (size_t)bt * BKT_CAP + pt));
        }
    }
}

__global__ __launch_bounds__(256) void bkt_scan(
    const int* __restrict__ bktCnt, int* __restrict__ bktBase,
    int* __restrict__ rpA, int* __restrict__ rpT)
{
    __shared__ int s[2][256];
    const int tid = threadIdx.x;
    for (int d = 0; d < 2; ++d) {
        int v = (tid < NBKT) ? min(bktCnt[d * NBKT + tid], BKT_CAP) : 0;
        s[0][tid] = v;
        __syncthreads();
        int sel = 0;
        for (int off = 1; off < 256; off <<= 1) {
            int t = s[sel][tid] + ((tid >= off) ? s[sel][tid - off] : 0);
            s[sel ^ 1][tid] = t;
            sel ^= 1;
            __syncthreads();
        }
        int incl = s[sel][tid];
        if (tid < NBKT) bktBase[d * NBKT + tid] = incl - v;
        if (tid == NBKT - 1) (d ? rpT : rpA)[N_NODES] = incl;
        __syncthreads();
    }
}

__global__ __launch_bounds__(256) void build_p2(
    const int* __restrict__ bktCnt, const int* __restrict__ bktBase,
    const uint2* __restrict__ stagedA, const uint2* __restrict__ stagedT,
    int* __restrict__ rpA, int* __restrict__ rpT,
    int2* __restrict__ cvA, int2* __restrict__ cvT)
{
    const int tid = threadIdx.x;
    int dir = (int)blockIdx.x >= NBKT;
    int b = blockIdx.x - dir * NBKT;
    int cnt = min(bktCnt[dir * NBKT + b], BKT_CAP);
    int cbase = bktBase[dir * NBKT + b];
    const uint2* staged = (dir ? stagedT : stagedA) + (size_t)b * BKT_CAP;
    int* rp = dir ? rpT : rpA;
    int2* cv = dir ? cvT : cvA;

    __shared__ int rc[256];
    __shared__ int s[2][256];
    rc[tid] = 0;
    __syncthreads();
    for (int i = tid; i < cnt; i += 256)
        atomicAdd(&rc[(staged[i].x >> 16) & 255], 1);
    __syncthreads();
    int own = rc[tid];
    s[0][tid] = own;
    __syncthreads();
    int sel = 0;
    for (int off = 1; off < 256; off <<= 1) {
        int t = s[sel][tid] + ((tid >= off) ? s[sel][tid - off] : 0);
        s[sel ^ 1][tid] = t;
        sel ^= 1;
        __syncthreads();
    }
    int ex = s[sel][tid] - own;
    int row = b * 256 + tid;
    if (row < N_NODES) rp[row] = cbase + ex;
    rc[tid] = ex;
    __syncthreads();
    for (int i = tid; i < cnt; i += 256) {
        uint2 rec = staged[i];
        int local = (rec.x >> 16) & 255;
        int pos = cbase + atomicAdd(&rc[local], 1);
        cv[pos] = make_int2((int)(rec.x & 0xFFFFu), (int)rec.y);
    }
}

// ===========================================================================
// Generic SpMM: 16 lanes per edge, 16B per lane. Per set:
//   t = M @ g16 ; optionally store a16=bf(t), m16=bf(t*s16), k16=bf(t+t*s16)
// Two sets per dispatch (blocks >= nA -> set B).
// ===========================================================================
struct SpSet {
    const int* rp;
    const int2* cv;
    const unsigned int* g16;
    const unsigned int* s16;
    unsigned int* a16;
    unsigned int* m16;
    unsigned int* k16;
};

__device__ __forceinline__ void sp_accum(float* acc, uint4 w, float v) {
    float2 f;
    f = unpack2bf(w.x); acc[0] = fmaf(v, f.x, acc[0]); acc[1] = fmaf(v, f.y, acc[1]);
    f = unpack2bf(w.y); acc[2] = fmaf(v, f.x, acc[2]); acc[3] = fmaf(v, f.y, acc[3]);
    f = unpack2bf(w.z); acc[4] = fmaf(v, f.x, acc[4]); acc[5] = fmaf(v, f.y, acc[5]);
    f = unpack2bf(w.w); acc[6] = fmaf(v, f.x, acc[6]); acc[7] = fmaf(v, f.y, acc[7]);
}

__global__ __launch_bounds__(256) void sp_multi(SpSet sA, SpSet sB, int nA)
{
    bool second = (int)blockIdx.x >= nA;
    SpSet st = second ? sB : sA;
    int blk = second ? (blockIdx.x - nA) : blockIdx.x;
    int row = blk * 4 + (threadIdx.x >> 6);
    if (row >= N_NODES) return;
    int lane = threadIdx.x & 63;
    int li = lane & 15;          // 16B chunk within row
    int sub = lane >> 4;         // edge sub-stream 0..3

    int b = st.rp[row], e = st.rp[row + 1];
    float acc[8] = {0.f, 0.f, 0.f, 0.f, 0.f, 0.f, 0.f, 0.f};

    int i = b + sub;
    for (; i + 4 < e; i += 8) {
        int2 c0 = st.cv[i];
        int2 c1 = st.cv[i + 4];
        uint4 w0 = *((const uint4*)(st.g16 + (size_t)c0.x * 64) + li);
        uint4 w1 = *((const uint4*)(st.g16 + (size_t)c1.x * 64) + li);
        sp_accum(acc, w0, __int_as_float(c0.y));
        sp_accum(acc, w1, __int_as_float(c1.y));
    }
    if (i < e) {
        int2 c = st.cv[i];
        uint4 w = *((const uint4*)(st.g16 + (size_t)c.x * 64) + li);
        sp_accum(acc, w, __int_as_float(c.y));
    }

    #pragma unroll
    for (int j = 0; j < 8; ++j) {
        acc[j] += __shfl_xor(acc[j], 16, 64);
        acc[j] += __shfl_xor(acc[j], 32, 64);
    }

    int o = row * 16 + li;       // uint4 index
    uint4 sv4 = ((const uint4*)st.s16)[o];
    float2 s0 = unpack2bf(sv4.x), s1 = unpack2bf(sv4.y);
    float2 s2 = unpack2bf(sv4.z), s3 = unpack2bf(sv4.w);
    float m[8] = {acc[0]*s0.x, acc[1]*s0.y, acc[2]*s1.x, acc[3]*s1.y,
                  acc[4]*s2.x, acc[5]*s2.y, acc[6]*s3.x, acc[7]*s3.y};

    if (sub == 0 && st.a16) {
        uint4 o4 = make_uint4(pack2bf(acc[0], acc[1]), pack2bf(acc[2], acc[3]),
                              pack2bf(acc[4], acc[5]), pack2bf(acc[6], acc[7]));
        ((uint4*)st.a16)[o] = o4;
    } else if (sub == 1 && st.m16) {
        uint4 o4 = make_uint4(pack2bf(m[0], m[1]), pack2bf(m[2], m[3]),
                              pack2bf(m[4], m[5]), pack2bf(m[6], m[7]));
        ((uint4*)st.m16)[o] = o4;
    } else if (sub == 2 && st.k16) {
        uint4 o4 = make_uint4(pack2bf(acc[0]+m[0], acc[1]+m[1]),
                              pack2bf(acc[2]+m[2], acc[3]+m[3]),
                              pack2bf(acc[4]+m[4], acc[5]+m[5]),
                              pack2bf(acc[6]+m[6], acc[7]+m[7]));
        ((uint4*)st.k16)[o] = o4;
    }
}

// ===========================================================================
// MFMA quad GEMM, direct-from-global A operands, no staging LDS.
// res = relu( X0@W1^T + X1@W1^T + X2@W2^T + X3@W2^T + 2*(b1+b2) )
// Block: 256 thr = 4 waves: (kh = K-half, nh = N-half). Each wave loads its
// own A fragments (16B global loads, L2/L3-hot), computes partial-K acc for
// 64 rows x 64 cols; kh=1 writes partials to padded LDS; kh=0 reduces + epi.
// ===========================================================================
struct G4 {
    const unsigned short* X[8];
    float* outf[2];
    unsigned short* o16[2];
};

__global__ __launch_bounds__(256) void gemm4_direct(
    G4 g, const float* __restrict__ W1, const float* __restrict__ W2,
    const float* __restrict__ b1, const float* __restrict__ b2, int nA)
{
    __shared__ float red[2][64][68];     // [nh][col][row + pad] = 34.8 KB

    int second = (int)blockIdx.x >= nA;
    int blk = blockIdx.x - second * nA;
    const int row0 = blk * 64;
    const int tid = threadIdx.x;
    const int wid = tid >> 6;
    const int lane = tid & 63;
    const int kh = wid & 1;
    const int nh = wid >> 1;
    const int lr = lane & 15;
    const int kgrp = lane >> 4;

    const unsigned short* Xb[4];
    #pragma unroll
    for (int t = 0; t < 4; ++t) Xb[t] = g.X[second * 4 + t];

    // W fragments: col = nh*64 + nt*16 + lr ; k = (kh*2+ks2)*32 + kgrp*8
    short8 wf[2][4][2];
    #pragma unroll
    for (int mat = 0; mat < 2; ++mat) {
        const float* W = mat ? W2 : W1;
        #pragma unroll
        for (int nt = 0; nt < 4; ++nt) {
            #pragma unroll
            for (int ks2 = 0; ks2 < 2; ++ks2) {
                const float* wp = W + (size_t)(nh * 64 + nt * 16 + lr) * DIM
                                    + (kh * 2 + ks2) * 32 + kgrp * 8;
                wf[mat][nt][ks2] = pack_bf8(*(const float4*)wp,
                                            *(const float4*)(wp + 4));
            }
        }
    }

    f32x4 acc[4][4];
    #pragma unroll
    for (int mt = 0; mt < 4; ++mt)
        #pragma unroll
        for (int nt = 0; nt < 4; ++nt)
            acc[mt][nt] = (f32x4){0.f, 0.f, 0.f, 0.f};

    #pragma unroll
    for (int xt = 0; xt < 4; ++xt) {
        const int wsel = xt >> 1;
        #pragma unroll
        for (int ks2 = 0; ks2 < 2; ++ks2) {
            short8 af[4];
            #pragma unroll
            for (int mt = 0; mt < 4; ++mt)
                af[mt] = *(const short8*)(Xb[xt]
                          + (size_t)(row0 + mt * 16 + lr) * DIM
                          + (kh * 2 + ks2) * 32 + kgrp * 8);
            #pragma unroll
            for (int mt = 0; mt < 4; ++mt)
                #pragma unroll
                for (int nt = 0; nt < 4; ++nt)
                    acc[mt][nt] = __builtin_amdgcn_mfma_f32_16x16x32_bf16(
                        af[mt], wf[wsel][nt][ks2], acc[mt][nt], 0, 0, 0);
        }
    }

    if (kh == 1) {
        #pragma unroll
        for (int mt = 0; mt < 4; ++mt)
            #pragma unroll
            for (int nt = 0; nt < 4; ++nt)
                *(f32x4*)&red[nh][nt * 16 + lr][mt * 16 + kgrp * 4] = acc[mt][nt];
    }
    __syncthreads();
    if (kh == 0) {
        float* outf = second ? g.outf[1] : g.outf[0];
        unsigned short* o16 = second ? g.o16[1] : g.o16[0];
        #pragma unroll
        for (int nt = 0; nt < 4; ++nt) {
            int col = nh * 64 + nt * 16 + lr;
            float c = 2.0f * (b1[col] + b2[col]);
            #pragma unroll
            for (int mt = 0; mt < 4; ++mt) {
                f32x4 r = *(const f32x4*)&red[nh][nt * 16 + lr][mt * 16 + kgrp * 4];
                #pragma unroll
                for (int j = 0; j < 4; ++j) {
                    int row = row0 + mt * 16 + kgrp * 4 + j;
                    float o = fmaxf(acc[mt][nt][j] + r[j] + c, 0.f);
                    if (outf) outf[(size_t)row * DIM + col] = o;
                    if (o16) o16[(size_t)row * DIM + col] = f2bf(o);
                }
            }
        }
    }
}

// ===========================================================================
extern "C" void kernel_launch(void* const* d_in, const int* in_sizes, int n_in,
                              void* d_out, int out_size, void* d_ws, size_t ws_size,
                              hipStream_t stream)
{
    const float* l_feat = (const float*)d_in[0];
    const float* r_feat = (const float*)d_in[1];
    const int*   rows   = (const int*)d_in[2];
    const int*   cols   = (const int*)d_in[3];
    const float* vals   = (const float*)d_in[4];
    const float* W1a    = (const float*)d_in[5];
    const float* b1a    = (const float*)d_in[6];
    const float* W2a    = (const float*)d_in[7];
    const float* b2a    = (const float*)d_in[8];
    const float* W1b    = (const float*)d_in[9];
    const float* b1b    = (const float*)d_in[10];
    const float* W2b    = (const float*)d_in[11];
    const float* b2b    = (const float*)d_in[12];
    float* out = (float*)d_out;

    const size_t NT = (size_t)N_NODES * DIM;
    const size_t MAT16 = NT * 2;

    char* p = (char*)d_ws;
    auto alloc = [&](size_t bytes) {
        char* q = p; p += (bytes + 255) & ~(size_t)255; return q;
    };
    unsigned int* l16 = (unsigned int*)alloc(MAT16);   // l_feat -> y1
    unsigned int* r16 = (unsigned int*)alloc(MAT16);   // r_feat -> z1
    unsigned int* Kl  = (unsigned int*)alloc(MAT16);
    unsigned int* Kr  = (unsigned int*)alloc(MAT16);
    unsigned int* a0L = (unsigned int*)alloc(MAT16);
    unsigned int* m0L = (unsigned int*)alloc(MAT16);
    unsigned int* a1L = (unsigned int*)alloc(MAT16);
    unsigned int* m1L = (unsigned int*)alloc(MAT16);
    unsigned int* a0R = (unsigned int*)alloc(MAT16);
    unsigned int* m0R = (unsigned int*)alloc(MAT16);
    unsigned int* a1R = (unsigned int*)alloc(MAT16);
    unsigned int* m1R = (unsigned int*)alloc(MAT16);
    int* rpA = (int*)alloc((size_t)(N_NODES + 1) * 4);
    int* rpT = (int*)alloc((size_t)(N_NODES + 1) * 4);
    int* bktCnt  = (int*)alloc((size_t)(2 * NBKT) * 4);
    int* bktBase = (int*)alloc((size_t)(2 * NBKT) * 4);
    int2* cvA = (int2*)alloc((size_t)E_EDGES * 8);
    int2* cvT = (int2*)alloc((size_t)E_EDGES * 8);
    uint2* stagedA = (uint2*)alloc((size_t)NBKT * BKT_CAP * 8);
    uint2* stagedT = (uint2*)alloc((size_t)NBKT * BKT_CAP * 8);

    const int n4 = (int)(NT / 4);
    dim3 blk(256);
    dim3 cvGrid((n4 + 255) / 256);
    const int spBlocks = (N_NODES + 3) / 4;        // 10000
    const int gmBlocks = N_NODES / 64;             // 625
    const int p1Blocks = (E_EDGES + 2047) / 2048;  // 313

    // ---- CSR build + bf16 conversion ----
    hipMemsetAsync(bktCnt, 0, (size_t)(2 * NBKT) * 4, stream);
    convert_kernel<<<cvGrid, blk, 0, stream>>>(
        (const float4*)l_feat, (const float4*)r_feat,
        (uint2*)l16, (uint2*)r16, n4);
    build_p1<<<dim3(p1Blocks), blk, 0, stream>>>(
        rows, cols, vals, bktCnt, stagedA, stagedT);
    bkt_scan<<<1, blk, 0, stream>>>(bktCnt, bktBase, rpA, rpT);
    build_p2<<<dim3(2 * NBKT), blk, 0, stream>>>(
        bktCnt, bktBase, stagedA, stagedT, rpA, rpT, cvA, cvT);

    // ======================= Layer A =======================
    {   // hop0: a0=A@r (store a,m,K) ; b0=AT@l (store a,m,K)
        SpSet h0A = {rpA, cvA, r16, l16, a0L, m0L, Kl};
        SpSet h0T = {rpT, cvT, l16, r16, a0R, m0R, Kr};
        sp_multi<<<dim3(2 * spBlocks), blk, 0, stream>>>(h0A, h0T, spBlocks);
    }
    {   // hop1: a1=A@Kr (store a,m vs Kl) ; b1=AT@Kl (store a,m vs Kr)
        SpSet h1A = {rpA, cvA, Kr, Kl, a1L, m1L, nullptr};
        SpSet h1T = {rpT, cvT, Kl, Kr, a1R, m1R, nullptr};
        sp_multi<<<dim3(2 * spBlocks), blk, 0, stream>>>(h1A, h1T, spBlocks);
    }
    {   // y1 -> l16 (bf16), z1 -> r16 (bf16)
        G4 g;
        g.X[0] = (const unsigned short*)a0L; g.X[1] = (const unsigned short*)a1L;
        g.X[2] = (const unsigned short*)m0L; g.X[3] = (const unsigned short*)m1L;
        g.X[4] = (const unsigned short*)a0R; g.X[5] = (const unsigned short*)a1R;
        g.X[6] = (const unsigned short*)m0R; g.X[7] = (const unsigned short*)m1R;
        g.outf[0] = nullptr; g.outf[1] = nullptr;
        g.o16[0] = (unsigned short*)l16;
        g.o16[1] = (unsigned short*)r16;
        gemm4_direct<<<dim3(2 * gmBlocks), blk, 0, stream>>>(
            g, W1a, W2a, b1a, b2a, gmBlocks);
    }

    // ======================= Layer B (l-output only) =======================
    {   // a=A@z1 (store a,m,Klb) ; b=AT@y1 (store Krb only)
        SpSet b0A = {rpA, cvA, r16, l16, a0L, m0L, Kl};
        SpSet b0T = {rpT, cvT, l16, r16, nullptr, nullptr, Kr};
        sp_multi<<<dim3(2 * spBlocks), blk, 0, stream>>>(b0A, b0T, spBlocks);
    }
    {   // a1=A@Krb (store a,m vs Klb)
        SpSet b1A = {rpA, cvA, Kr, Kl, a1L, m1L, nullptr};
        sp_multi<<<dim3(spBlocks), blk, 0, stream>>>(b1A, b1A, spBlocks);
    }
    {   // out = relu((a0+a1)@W1b^T + (m0+m1)@W2b^T + 2(b1b+b2b))  [fp32]
        G4 g;
        g.X[0] = (const unsigned short*)a0L; g.X[1] = (const unsigned short*)a1L;
        g.X[2] = (const unsigned short*)m0L; g.X[3] = (const unsigned short*)m1L;
        g.X[4] = g.X[0]; g.X[5] = g.X[1]; g.X[6] = g.X[2]; g.X[7] = g.X[3];
        g.outf[0] = out; g.outf[1] = nullptr;
        g.o16[0] = nullptr; g.o16[1] = nullptr;
        gemm4_direct<<<dim3(gmBlocks), blk, 0, stream>>>(
            g, W1b, W2b, b1b, b2b, gmBlocks);
    }
}

// Round 7
// 326.137 us; speedup vs baseline: 24.2993x; 1.0359x over previous
//
#include <hip/hip_runtime.h>

#define N_NODES 40000
#define E_EDGES 640000
#define DIM 128
#define NBKT 157            // buckets of 256 rows
#define BKT_CAP 6144

typedef __attribute__((ext_vector_type(8))) short short8;
typedef __attribute__((ext_vector_type(4))) float f32x4;

__device__ __forceinline__ unsigned short f2bf(float f) {
    unsigned int u = __float_as_uint(f);
    u = u + 0x7FFFu + ((u >> 16) & 1u);
    return (unsigned short)(u >> 16);
}
__device__ __forceinline__ unsigned int pack2bf(float lo, float hi) {
    return (unsigned int)f2bf(lo) | ((unsigned int)f2bf(hi) << 16);
}
__device__ __forceinline__ float2 unpack2bf(unsigned int u) {
    return make_float2(__uint_as_float(u << 16), __uint_as_float(u & 0xFFFF0000u));
}
__device__ __forceinline__ short8 pack_bf8(float4 a, float4 b) {
    short8 r;
    r[0] = (short)f2bf(a.x); r[1] = (short)f2bf(a.y);
    r[2] = (short)f2bf(a.z); r[3] = (short)f2bf(a.w);
    r[4] = (short)f2bf(b.x); r[5] = (short)f2bf(b.y);
    r[6] = (short)f2bf(b.z); r[7] = (short)f2bf(b.w);
    return r;
}

// ===========================================================================
// fp32 -> bf16 feature conversion
// ===========================================================================
__global__ __launch_bounds__(256) void convert_kernel(
    const float4* __restrict__ lf, const float4* __restrict__ rf,
    uint2* __restrict__ l16, uint2* __restrict__ r16, int n4)
{
    int i = blockIdx.x * 256 + threadIdx.x;
    if (i >= n4) return;
    float4 a = lf[i];
    float4 b = rf[i];
    l16[i] = make_uint2(pack2bf(a.x, a.y), pack2bf(a.z, a.w));
    r16[i] = make_uint2(pack2bf(b.x, b.y), pack2bf(b.z, b.w));
}

// ===========================================================================
// CSR build phase 1: LDS-aggregated bucket partition (both directions)
// ===========================================================================
__global__ __launch_bounds__(256) void build_p1(
    const int* __restrict__ rows, const int* __restrict__ cols,
    const float* __restrict__ vals,
    int* __restrict__ bktCnt,
    uint2* __restrict__ stagedA, uint2* __restrict__ stagedT)
{
    __shared__ int cA[NBKT], cT[NBKT], bA[NBKT], bT[NBKT];
    const int tid = threadIdx.x;
    for (int i = tid; i < NBKT; i += 256) { cA[i] = 0; cT[i] = 0; }
    __syncthreads();

    int r[8], c[8];
    unsigned int v[8];
    const int base = blockIdx.x * 2048 + tid;
    #pragma unroll
    for (int k = 0; k < 8; ++k) {
        int e = base + k * 256;
        bool ok = e < E_EDGES;
        r[k] = ok ? __builtin_nontemporal_load(rows + e) : -1;
        c[k] = ok ? __builtin_nontemporal_load(cols + e) : 0;
        v[k] = ok ? __float_as_uint(__builtin_nontemporal_load(vals + e)) : 0u;
        if (ok) {
            atomicAdd(&cA[r[k] >> 8], 1);
            atomicAdd(&cT[c[k] >> 8], 1);
        }
    }
    __syncthreads();
    for (int i = tid; i < NBKT; i += 256) {
        bA[i] = atomicAdd(&bktCnt[i], cA[i]);
        bT[i] = atomicAdd(&bktCnt[NBKT + i], cT[i]);
        cA[i] = 0; cT[i] = 0;
    }
    __syncthreads();
    #pragma unroll
    for (int k = 0; k < 8; ++k) {
        if (r[k] < 0) continue;
        int ba = r[k] >> 8;
        int pa = bA[ba] + atomicAdd(&cA[ba], 1);
        if (pa < BKT_CAP) {
            unsigned long long rec =
                ((unsigned long long)v[k] << 32) |
                (((unsigned)r[k] << 16) | (unsigned)c[k]);
            __builtin_nontemporal_store(rec,
                (unsigned long long*)(stagedA + (size_t)ba * BKT_CAP + pa));
        }
        int bt = c[k] >> 8;
        int pt = bT[bt] + atomicAdd(&cT[bt], 1);
        if (pt < BKT_CAP) {
            unsigned long long rec =
                ((unsigned long long)v[k] << 32) |
                (((unsigned)c[k] << 16) | (unsigned)r[k]);
            __builtin_nontemporal_store(rec,
                (unsigned long long*)(stagedT + (size_t)bt * BKT_CAP + pt));
        }
    }
}

__global__ __launch_bounds__(256) void bkt_scan(
    const int* __restrict__ bktCnt, int* __restrict__ bktBase,
    int* __restrict__ rpA, int* __restrict__ rpT)
{
    __shared__ int s[2][256];
    const int tid = threadIdx.x;
    for (int d = 0; d < 2; ++d) {
        int v = (tid < NBKT) ? min(bktCnt[d * NBKT + tid], BKT_CAP) : 0;
        s[0][tid] = v;
        __syncthreads();
        int sel = 0;
        for (int off = 1; off < 256; off <<= 1) {
            int t = s[sel][tid] + ((tid >= off) ? s[sel][tid - off] : 0);
            s[sel ^ 1][tid] = t;
            sel ^= 1;
            __syncthreads();
        }
        int incl = s[sel][tid];
        if (tid < NBKT) bktBase[d * NBKT + tid] = incl - v;
        if (tid == NBKT - 1) (d ? rpT : rpA)[N_NODES] = incl;
        __syncthreads();
    }
}

__global__ __launch_bounds__(256) void build_p2(
    const int* __restrict__ bktCnt, const int* __restrict__ bktBase,
    const uint2* __restrict__ stagedA, const uint2* __restrict__ stagedT,
    int* __restrict__ rpA, int* __restrict__ rpT,
    int2* __restrict__ cvA, int2* __restrict__ cvT)
{
    const int tid = threadIdx.x;
    int dir = (int)blockIdx.x >= NBKT;
    int b = blockIdx.x - dir * NBKT;
    int cnt = min(bktCnt[dir * NBKT + b], BKT_CAP);
    int cbase = bktBase[dir * NBKT + b];
    const uint2* staged = (dir ? stagedT : stagedA) + (size_t)b * BKT_CAP;
    int* rp = dir ? rpT : rpA;
    int2* cv = dir ? cvT : cvA;

    __shared__ int rc[256];
    __shared__ int s[2][256];
    rc[tid] = 0;
    __syncthreads();
    for (int i = tid; i < cnt; i += 256)
        atomicAdd(&rc[(staged[i].x >> 16) & 255], 1);
    __syncthreads();
    int own = rc[tid];
    s[0][tid] = own;
    __syncthreads();
    int sel = 0;
    for (int off = 1; off < 256; off <<= 1) {
        int t = s[sel][tid] + ((tid >= off) ? s[sel][tid - off] : 0);
        s[sel ^ 1][tid] = t;
        sel ^= 1;
        __syncthreads();
    }
    int ex = s[sel][tid] - own;
    int row = b * 256 + tid;
    if (row < N_NODES) rp[row] = cbase + ex;
    rc[tid] = ex;
    __syncthreads();
    for (int i = tid; i < cnt; i += 256) {
        uint2 rec = staged[i];
        int local = (rec.x >> 16) & 255;
        int pos = cbase + atomicAdd(&rc[local], 1);
        cv[pos] = make_int2((int)(rec.x & 0xFFFFu), (int)rec.y);
    }
}

// ===========================================================================
// Generic SpMM: 16 lanes/edge, 16B/lane. t = M @ g16, m = t * s16.
// Optional prior accumulation: asum = pa + t, msum = pm + m (in-place safe).
// Stores (nullable): a16 = bf(asum), m16 = bf(msum), k16 = bf(t + m).
// Two sets per dispatch (blocks >= nA -> set B).
// ===========================================================================
struct SpSet {
    const int* rp;
    const int2* cv;
    const unsigned int* g16;
    const unsigned int* s16;
    const unsigned int* pa16;   // prior a (or null)
    const unsigned int* pm16;   // prior m (or null)
    unsigned int* a16;
    unsigned int* m16;
    unsigned int* k16;
};

__device__ __forceinline__ void sp_accum(float* acc, uint4 w, float v) {
    float2 f;
    f = unpack2bf(w.x); acc[0] = fmaf(v, f.x, acc[0]); acc[1] = fmaf(v, f.y, acc[1]);
    f = unpack2bf(w.y); acc[2] = fmaf(v, f.x, acc[2]); acc[3] = fmaf(v, f.y, acc[3]);
    f = unpack2bf(w.z); acc[4] = fmaf(v, f.x, acc[4]); acc[5] = fmaf(v, f.y, acc[5]);
    f = unpack2bf(w.w); acc[6] = fmaf(v, f.x, acc[6]); acc[7] = fmaf(v, f.y, acc[7]);
}

__global__ __launch_bounds__(256) void sp_multi(SpSet sA, SpSet sB, int nA)
{
    bool second = (int)blockIdx.x >= nA;
    SpSet st = second ? sB : sA;
    int blk = second ? (blockIdx.x - nA) : blockIdx.x;
    int row = blk * 4 + (threadIdx.x >> 6);
    if (row >= N_NODES) return;
    int lane = threadIdx.x & 63;
    int li = lane & 15;
    int sub = lane >> 4;

    int b = st.rp[row], e = st.rp[row + 1];
    float acc[8] = {0.f, 0.f, 0.f, 0.f, 0.f, 0.f, 0.f, 0.f};

    int i = b + sub;
    for (; i + 4 < e; i += 8) {
        int2 c0 = st.cv[i];
        int2 c1 = st.cv[i + 4];
        uint4 w0 = *((const uint4*)(st.g16 + (size_t)c0.x * 64) + li);
        uint4 w1 = *((const uint4*)(st.g16 + (size_t)c1.x * 64) + li);
        sp_accum(acc, w0, __int_as_float(c0.y));
        sp_accum(acc, w1, __int_as_float(c1.y));
    }
    if (i < e) {
        int2 c = st.cv[i];
        uint4 w = *((const uint4*)(st.g16 + (size_t)c.x * 64) + li);
        sp_accum(acc, w, __int_as_float(c.y));
    }

    #pragma unroll
    for (int j = 0; j < 8; ++j) {
        acc[j] += __shfl_xor(acc[j], 16, 64);
        acc[j] += __shfl_xor(acc[j], 32, 64);
    }

    int o = row * 16 + li;       // uint4 index
    uint4 sv4 = ((const uint4*)st.s16)[o];
    float2 s0 = unpack2bf(sv4.x), s1 = unpack2bf(sv4.y);
    float2 s2 = unpack2bf(sv4.z), s3 = unpack2bf(sv4.w);
    float m[8] = {acc[0]*s0.x, acc[1]*s0.y, acc[2]*s1.x, acc[3]*s1.y,
                  acc[4]*s2.x, acc[5]*s2.y, acc[6]*s3.x, acc[7]*s3.y};

    if (sub == 0 && st.a16) {
        float a[8] = {acc[0], acc[1], acc[2], acc[3], acc[4], acc[5], acc[6], acc[7]};
        if (st.pa16) {
            uint4 pv = ((const uint4*)st.pa16)[o];
            float2 p0 = unpack2bf(pv.x), p1 = unpack2bf(pv.y);
            float2 p2 = unpack2bf(pv.z), p3 = unpack2bf(pv.w);
            a[0] += p0.x; a[1] += p0.y; a[2] += p1.x; a[3] += p1.y;
            a[4] += p2.x; a[5] += p2.y; a[6] += p3.x; a[7] += p3.y;
        }
        uint4 o4 = make_uint4(pack2bf(a[0], a[1]), pack2bf(a[2], a[3]),
                              pack2bf(a[4], a[5]), pack2bf(a[6], a[7]));
        ((uint4*)st.a16)[o] = o4;
    } else if (sub == 1 && st.m16) {
        float q[8] = {m[0], m[1], m[2], m[3], m[4], m[5], m[6], m[7]};
        if (st.pm16) {
            uint4 pv = ((const uint4*)st.pm16)[o];
            float2 p0 = unpack2bf(pv.x), p1 = unpack2bf(pv.y);
            float2 p2 = unpack2bf(pv.z), p3 = unpack2bf(pv.w);
            q[0] += p0.x; q[1] += p0.y; q[2] += p1.x; q[3] += p1.y;
            q[4] += p2.x; q[5] += p2.y; q[6] += p3.x; q[7] += p3.y;
        }
        uint4 o4 = make_uint4(pack2bf(q[0], q[1]), pack2bf(q[2], q[3]),
                              pack2bf(q[4], q[5]), pack2bf(q[6], q[7]));
        ((uint4*)st.m16)[o] = o4;
    } else if (sub == 2 && st.k16) {
        uint4 o4 = make_uint4(pack2bf(acc[0]+m[0], acc[1]+m[1]),
                              pack2bf(acc[2]+m[2], acc[3]+m[3]),
                              pack2bf(acc[4]+m[4], acc[5]+m[5]),
                              pack2bf(acc[6]+m[6], acc[7]+m[7]));
        ((uint4*)st.k16)[o] = o4;
    }
}

// ===========================================================================
// MFMA double GEMM, fragment-linear LDS (conflict-free reads AND writes):
//   res = relu( X1@W1^T + X2@W2^T + 2*(b1+b2) )
// LDS addr = ((ks*4+mt)*64 + (kgrp*16+lr))*16 ^ (ks<<5):
//   read slot (lane&7)^2ks, write slot (lr&7)^2ks -> both uniform 8 lanes/slot.
// Two sets per dispatch (blocks >= nA -> set B). 32 KB LDS -> 4 blocks/CU.
// ===========================================================================
struct G2 {
    const unsigned short* X1[2];
    const unsigned short* X2[2];
    float* outf[2];
    unsigned short* o16[2];
};

__global__ __launch_bounds__(256) void gemm2f(
    G2 g, const float* __restrict__ W1, const float* __restrict__ W2,
    const float* __restrict__ b1, const float* __restrict__ b2, int nA)
{
    __shared__ unsigned short xs[2][64 * DIM];   // 32 KB

    int second = (int)blockIdx.x >= nA;
    int blk = blockIdx.x - second * nA;
    const int row0 = blk * 64;
    const int tid = threadIdx.x;

    const unsigned short* Xs0 = g.X1[second];
    const unsigned short* Xs1 = g.X2[second];
    #pragma unroll
    for (int t = 0; t < 2; ++t) {
        const unsigned short* X = t ? Xs1 : Xs0;
        #pragma unroll
        for (int it = 0; it < 4; ++it) {
            int id = tid + 256 * it;
            int r = id >> 4, c16 = id & 15;
            int ks = c16 >> 2, kgrp = c16 & 3;
            int mt = r >> 4, lr = r & 15;
            int addr = ((((ks * 4 + mt) * 64) + kgrp * 16 + lr) * 16) ^ (ks << 5);
            uint4 d = *(const uint4*)(X + (size_t)(row0 + r) * DIM + c16 * 8);
            *(uint4*)((char*)&xs[t][0] + addr) = d;
        }
    }

    const int wv = tid >> 6;
    const int lane = tid & 63;
    const int lr = lane & 15;
    const int kgrp = lane >> 4;
    const int colbase = wv * 32;

    // W fragments in registers: col = colbase + nt*16 + lr, k = ks*32 + kgrp*8
    short8 wf[2][2][4];
    #pragma unroll
    for (int mat = 0; mat < 2; ++mat) {
        const float* W = mat ? W2 : W1;
        #pragma unroll
        for (int nt = 0; nt < 2; ++nt) {
            #pragma unroll
            for (int ks = 0; ks < 4; ++ks) {
                const float* wp = W + (size_t)(colbase + nt * 16 + lr) * DIM
                                    + ks * 32 + kgrp * 8;
                wf[mat][nt][ks] = pack_bf8(*(const float4*)wp,
                                           *(const float4*)(wp + 4));
            }
        }
    }

    __syncthreads();

    f32x4 acc[4][2];
    #pragma unroll
    for (int mt = 0; mt < 4; ++mt)
        #pragma unroll
        for (int nt = 0; nt < 2; ++nt)
            acc[mt][nt] = (f32x4){0.f, 0.f, 0.f, 0.f};

    #pragma unroll
    for (int ks = 0; ks < 4; ++ks) {
        short8 a1f[4], a2f[4];
        #pragma unroll
        for (int mt = 0; mt < 4; ++mt) {
            int addr = ((((ks * 4 + mt) * 64) + lane) * 16) ^ (ks << 5);
            a1f[mt] = *(const short8*)((const char*)&xs[0][0] + addr);
            a2f[mt] = *(const short8*)((const char*)&xs[1][0] + addr);
        }
        #pragma unroll
        for (int mt = 0; mt < 4; ++mt) {
            #pragma unroll
            for (int nt = 0; nt < 2; ++nt) {
                acc[mt][nt] = __builtin_amdgcn_mfma_f32_16x16x32_bf16(
                    a1f[mt], wf[0][nt][ks], acc[mt][nt], 0, 0, 0);
                acc[mt][nt] = __builtin_amdgcn_mfma_f32_16x16x32_bf16(
                    a2f[mt], wf[1][nt][ks], acc[mt][nt], 0, 0, 0);
            }
        }
    }

    float* outf = g.outf[second];
    unsigned short* o16 = g.o16[second];
    #pragma unroll
    for (int nt = 0; nt < 2; ++nt) {
        int col = colbase + nt * 16 + lr;
        float c = 2.0f * (b1[col] + b2[col]);
        #pragma unroll
        for (int mt = 0; mt < 4; ++mt) {
            #pragma unroll
            for (int r = 0; r < 4; ++r) {
                int row = row0 + mt * 16 + kgrp * 4 + r;
                float o = fmaxf(acc[mt][nt][r] + c, 0.f);
                if (outf) outf[(size_t)row * DIM + col] = o;
                if (o16) o16[(size_t)row * DIM + col] = f2bf(o);
            }
        }
    }
}

// ===========================================================================
extern "C" void kernel_launch(void* const* d_in, const int* in_sizes, int n_in,
                              void* d_out, int out_size, void* d_ws, size_t ws_size,
                              hipStream_t stream)
{
    const float* l_feat = (const float*)d_in[0];
    const float* r_feat = (const float*)d_in[1];
    const int*   rows   = (const int*)d_in[2];
    const int*   cols   = (const int*)d_in[3];
    const float* vals   = (const float*)d_in[4];
    const float* W1a    = (const float*)d_in[5];
    const float* b1a    = (const float*)d_in[6];
    const float* W2a    = (const float*)d_in[7];
    const float* b2a    = (const float*)d_in[8];
    const float* W1b    = (const float*)d_in[9];
    const float* b1b    = (const float*)d_in[10];
    const float* W2b    = (const float*)d_in[11];
    const float* b2b    = (const float*)d_in[12];
    float* out = (float*)d_out;

    const size_t NT = (size_t)N_NODES * DIM;
    const size_t MAT16 = NT * 2;

    char* p = (char*)d_ws;
    auto alloc = [&](size_t bytes) {
        char* q = p; p += (bytes + 255) & ~(size_t)255; return q;
    };
    unsigned int* l16 = (unsigned int*)alloc(MAT16);   // l_feat -> y1
    unsigned int* r16 = (unsigned int*)alloc(MAT16);   // r_feat -> z1
    unsigned int* Kl  = (unsigned int*)alloc(MAT16);
    unsigned int* Kr  = (unsigned int*)alloc(MAT16);
    unsigned int* aL  = (unsigned int*)alloc(MAT16);   // a-sum (L)
    unsigned int* mL  = (unsigned int*)alloc(MAT16);   // m-sum (L)
    unsigned int* aR  = (unsigned int*)alloc(MAT16);   // a-sum (R)
    unsigned int* mR  = (unsigned int*)alloc(MAT16);   // m-sum (R)
    int* rpA = (int*)alloc((size_t)(N_NODES + 1) * 4);
    int* rpT = (int*)alloc((size_t)(N_NODES + 1) * 4);
    int* bktCnt  = (int*)alloc((size_t)(2 * NBKT) * 4);
    int* bktBase = (int*)alloc((size_t)(2 * NBKT) * 4);
    int2* cvA = (int2*)alloc((size_t)E_EDGES * 8);
    int2* cvT = (int2*)alloc((size_t)E_EDGES * 8);
    uint2* stagedA = (uint2*)alloc((size_t)NBKT * BKT_CAP * 8);
    uint2* stagedT = (uint2*)alloc((size_t)NBKT * BKT_CAP * 8);

    const int n4 = (int)(NT / 4);
    dim3 blk(256);
    dim3 cvGrid((n4 + 255) / 256);
    const int spBlocks = (N_NODES + 3) / 4;        // 10000
    const int gmBlocks = N_NODES / 64;             // 625
    const int p1Blocks = (E_EDGES + 2047) / 2048;  // 313

    // ---- CSR build + bf16 conversion ----
    hipMemsetAsync(bktCnt, 0, (size_t)(2 * NBKT) * 4, stream);
    convert_kernel<<<cvGrid, blk, 0, stream>>>(
        (const float4*)l_feat, (const float4*)r_feat,
        (uint2*)l16, (uint2*)r16, n4);
    build_p1<<<dim3(p1Blocks), blk, 0, stream>>>(
        rows, cols, vals, bktCnt, stagedA, stagedT);
    bkt_scan<<<1, blk, 0, stream>>>(bktCnt, bktBase, rpA, rpT);
    build_p2<<<dim3(2 * NBKT), blk, 0, stream>>>(
        bktCnt, bktBase, stagedA, stagedT, rpA, rpT, cvA, cvT);

    // ======================= Layer A =======================
    {   // hop0: a0=A@r (store a,m,Kl) ; b0=AT@l (store a,m,Kr)
        SpSet h0A = {rpA, cvA, r16, l16, nullptr, nullptr, aL, mL, Kl};
        SpSet h0T = {rpT, cvT, l16, r16, nullptr, nullptr, aR, mR, Kr};
        sp_multi<<<dim3(2 * spBlocks), blk, 0, stream>>>(h0A, h0T, spBlocks);
    }
    {   // hop1 (accumulate in place): aL=bf(aL+t), mL=bf(mL+t*Kl); same for R
        SpSet h1A = {rpA, cvA, Kr, Kl, aL, mL, aL, mL, nullptr};
        SpSet h1T = {rpT, cvT, Kl, Kr, aR, mR, aR, mR, nullptr};
        sp_multi<<<dim3(2 * spBlocks), blk, 0, stream>>>(h1A, h1T, spBlocks);
    }
    {   // y1 -> l16 (bf16), z1 -> r16 (bf16)
        G2 g;
        g.X1[0] = (const unsigned short*)aL; g.X2[0] = (const unsigned short*)mL;
        g.X1[1] = (const unsigned short*)aR; g.X2[1] = (const unsigned short*)mR;
        g.outf[0] = nullptr; g.outf[1] = nullptr;
        g.o16[0] = (unsigned short*)l16;
        g.o16[1] = (unsigned short*)r16;
        gemm2f<<<dim3(2 * gmBlocks), blk, 0, stream>>>(
            g, W1a, W2a, b1a, b2a, gmBlocks);
    }

    // ======================= Layer B (l-output only) =======================
    {   // a=A@z1 (store a,m,Klb) ; b=AT@y1 (store Krb only)
        SpSet b0A = {rpA, cvA, r16, l16, nullptr, nullptr, aL, mL, Kl};
        SpSet b0T = {rpT, cvT, l16, r16, nullptr, nullptr, nullptr, nullptr, Kr};
        sp_multi<<<dim3(2 * spBlocks), blk, 0, stream>>>(b0A, b0T, spBlocks);
    }
    {   // hop1: aL=bf(aL+t), mL=bf(mL+t*Klb)
        SpSet b1A = {rpA, cvA, Kr, Kl, aL, mL, aL, mL, nullptr};
        sp_multi<<<dim3(spBlocks), blk, 0, stream>>>(b1A, b1A, spBlocks);
    }
    {   // out = relu(aL@W1b^T + mL@W2b^T + 2(b1b+b2b))  [fp32]
        G2 g;
        g.X1[0] = (const unsigned short*)aL; g.X2[0] = (const unsigned short*)mL;
        g.X1[1] = g.X1[0]; g.X2[1] = g.X2[0];
        g.outf[0] = out; g.outf[1] = nullptr;
        g.o16[0] = nullptr; g.o16[1] = nullptr;
        gemm2f<<<dim3(gmBlocks), blk, 0, stream>>>(
            g, W1b, W2b, b1b, b2b, gmBlocks);
    }
}

// Round 8
// 313.466 us; speedup vs baseline: 25.2815x; 1.0404x over previous
//
#include <hip/hip_runtime.h>

#define N_NODES 40000
#define E_EDGES 640000
#define DIM 128
#define NBKT 157            // buckets of 256 rows
#define BKT_CAP 6144

typedef __attribute__((ext_vector_type(8))) short short8;
typedef __attribute__((ext_vector_type(4))) float f32x4;

__device__ __forceinline__ unsigned short f2bf(float f) {
    unsigned int u = __float_as_uint(f);
    u = u + 0x7FFFu + ((u >> 16) & 1u);
    return (unsigned short)(u >> 16);
}
__device__ __forceinline__ unsigned int pack2bf(float lo, float hi) {
    return (unsigned int)f2bf(lo) | ((unsigned int)f2bf(hi) << 16);
}
__device__ __forceinline__ float2 unpack2bf(unsigned int u) {
    return make_float2(__uint_as_float(u << 16), __uint_as_float(u & 0xFFFF0000u));
}
__device__ __forceinline__ short8 pack_bf8(float4 a, float4 b) {
    short8 r;
    r[0] = (short)f2bf(a.x); r[1] = (short)f2bf(a.y);
    r[2] = (short)f2bf(a.z); r[3] = (short)f2bf(a.w);
    r[4] = (short)f2bf(b.x); r[5] = (short)f2bf(b.y);
    r[6] = (short)f2bf(b.z); r[7] = (short)f2bf(b.w);
    return r;
}

// ===========================================================================
// fp32 -> bf16 feature conversion
// ===========================================================================
__global__ __launch_bounds__(256) void convert_kernel(
    const float4* __restrict__ lf, const float4* __restrict__ rf,
    uint2* __restrict__ l16, uint2* __restrict__ r16, int n4)
{
    int i = blockIdx.x * 256 + threadIdx.x;
    if (i >= n4) return;
    float4 a = lf[i];
    float4 b = rf[i];
    l16[i] = make_uint2(pack2bf(a.x, a.y), pack2bf(a.z, a.w));
    r16[i] = make_uint2(pack2bf(b.x, b.y), pack2bf(b.z, b.w));
}

// ===========================================================================
// CSR build phase 1: LDS-aggregated bucket partition (both directions)
// ===========================================================================
__global__ __launch_bounds__(256) void build_p1(
    const int* __restrict__ rows, const int* __restrict__ cols,
    const float* __restrict__ vals,
    int* __restrict__ bktCnt,
    uint2* __restrict__ stagedA, uint2* __restrict__ stagedT)
{
    __shared__ int cA[NBKT], cT[NBKT], bA[NBKT], bT[NBKT];
    const int tid = threadIdx.x;
    for (int i = tid; i < NBKT; i += 256) { cA[i] = 0; cT[i] = 0; }
    __syncthreads();

    int r[8], c[8];
    unsigned int v[8];
    const int base = blockIdx.x * 2048 + tid;
    #pragma unroll
    for (int k = 0; k < 8; ++k) {
        int e = base + k * 256;
        bool ok = e < E_EDGES;
        r[k] = ok ? __builtin_nontemporal_load(rows + e) : -1;
        c[k] = ok ? __builtin_nontemporal_load(cols + e) : 0;
        v[k] = ok ? __float_as_uint(__builtin_nontemporal_load(vals + e)) : 0u;
        if (ok) {
            atomicAdd(&cA[r[k] >> 8], 1);
            atomicAdd(&cT[c[k] >> 8], 1);
        }
    }
    __syncthreads();
    for (int i = tid; i < NBKT; i += 256) {
        bA[i] = atomicAdd(&bktCnt[i], cA[i]);
        bT[i] = atomicAdd(&bktCnt[NBKT + i], cT[i]);
        cA[i] = 0; cT[i] = 0;
    }
    __syncthreads();
    #pragma unroll
    for (int k = 0; k < 8; ++k) {
        if (r[k] < 0) continue;
        int ba = r[k] >> 8;
        int pa = bA[ba] + atomicAdd(&cA[ba], 1);
        if (pa < BKT_CAP) {
            unsigned long long rec =
                ((unsigned long long)v[k] << 32) |
                (((unsigned)r[k] << 16) | (unsigned)c[k]);
            __builtin_nontemporal_store(rec,
                (unsigned long long*)(stagedA + (size_t)ba * BKT_CAP + pa));
        }
        int bt = c[k] >> 8;
        int pt = bT[bt] + atomicAdd(&cT[bt], 1);
        if (pt < BKT_CAP) {
            unsigned long long rec =
                ((unsigned long long)v[k] << 32) |
                (((unsigned)c[k] << 16) | (unsigned)r[k]);
            __builtin_nontemporal_store(rec,
                (unsigned long long*)(stagedT + (size_t)bt * BKT_CAP + pt));
        }
    }
}

__global__ __launch_bounds__(256) void bkt_scan(
    const int* __restrict__ bktCnt, int* __restrict__ bktBase,
    int* __restrict__ rpA, int* __restrict__ rpT)
{
    __shared__ int s[2][256];
    const int tid = threadIdx.x;
    for (int d = 0; d < 2; ++d) {
        int v = (tid < NBKT) ? min(bktCnt[d * NBKT + tid], BKT_CAP) : 0;
        s[0][tid] = v;
        __syncthreads();
        int sel = 0;
        for (int off = 1; off < 256; off <<= 1) {
            int t = s[sel][tid] + ((tid >= off) ? s[sel][tid - off] : 0);
            s[sel ^ 1][tid] = t;
            sel ^= 1;
            __syncthreads();
        }
        int incl = s[sel][tid];
        if (tid < NBKT) bktBase[d * NBKT + tid] = incl - v;
        if (tid == NBKT - 1) (d ? rpT : rpA)[N_NODES] = incl;
        __syncthreads();
    }
}

__global__ __launch_bounds__(256) void build_p2(
    const int* __restrict__ bktCnt, const int* __restrict__ bktBase,
    const uint2* __restrict__ stagedA, const uint2* __restrict__ stagedT,
    int* __restrict__ rpA, int* __restrict__ rpT,
    int2* __restrict__ cvA, int2* __restrict__ cvT)
{
    const int tid = threadIdx.x;
    int dir = (int)blockIdx.x >= NBKT;
    int b = blockIdx.x - dir * NBKT;
    int cnt = min(bktCnt[dir * NBKT + b], BKT_CAP);
    int cbase = bktBase[dir * NBKT + b];
    const uint2* staged = (dir ? stagedT : stagedA) + (size_t)b * BKT_CAP;
    int* rp = dir ? rpT : rpA;
    int2* cv = dir ? cvT : cvA;

    __shared__ int rc[256];
    __shared__ int s[2][256];
    rc[tid] = 0;
    __syncthreads();
    for (int i = tid; i < cnt; i += 256)
        atomicAdd(&rc[(staged[i].x >> 16) & 255], 1);
    __syncthreads();
    int own = rc[tid];
    s[0][tid] = own;
    __syncthreads();
    int sel = 0;
    for (int off = 1; off < 256; off <<= 1) {
        int t = s[sel][tid] + ((tid >= off) ? s[sel][tid - off] : 0);
        s[sel ^ 1][tid] = t;
        sel ^= 1;
        __syncthreads();
    }
    int ex = s[sel][tid] - own;
    int row = b * 256 + tid;
    if (row < N_NODES) rp[row] = cbase + ex;
    rc[tid] = ex;
    __syncthreads();
    for (int i = tid; i < cnt; i += 256) {
        uint2 rec = staged[i];
        int local = (rec.x >> 16) & 255;
        int pos = cbase + atomicAdd(&rc[local], 1);
        // store col as BYTE offset (col * 256) for cheap gather addressing
        cv[pos] = make_int2((int)((rec.x & 0xFFFFu) << 8), (int)rec.y);
    }
}

// ===========================================================================
// Generic SpMM: 16 lanes/edge, 16B/lane, 4 edge sub-streams, 4-deep gather
// batching (16 random gathers in flight per wave).
//   t = M @ g16 ; m = t * s16
// Optional prior accumulation: a = pa + t, q = pm + m (in-place safe).
// Stores (nullable): a16 = bf(a), m16 = bf(q), k16 = bf(t + m).
// cv.x holds col*256 (byte offset). Two sets per dispatch (blocks>=nA -> B).
// ===========================================================================
struct SpSet {
    const int* rp;
    const int2* cv;
    const unsigned int* g16;
    const unsigned int* s16;
    const unsigned int* pa16;   // prior a (or null)
    const unsigned int* pm16;   // prior m (or null)
    unsigned int* a16;
    unsigned int* m16;
    unsigned int* k16;
};

__device__ __forceinline__ void sp_accum(float* acc, uint4 w, float v) {
    float2 f;
    f = unpack2bf(w.x); acc[0] = fmaf(v, f.x, acc[0]); acc[1] = fmaf(v, f.y, acc[1]);
    f = unpack2bf(w.y); acc[2] = fmaf(v, f.x, acc[2]); acc[3] = fmaf(v, f.y, acc[3]);
    f = unpack2bf(w.z); acc[4] = fmaf(v, f.x, acc[4]); acc[5] = fmaf(v, f.y, acc[5]);
    f = unpack2bf(w.w); acc[6] = fmaf(v, f.x, acc[6]); acc[7] = fmaf(v, f.y, acc[7]);
}

__global__ __launch_bounds__(256) void sp_multi(SpSet sA, SpSet sB, int nA)
{
    bool second = (int)blockIdx.x >= nA;
    SpSet st = second ? sB : sA;
    int blk = second ? (blockIdx.x - nA) : blockIdx.x;
    int row = blk * 4 + (threadIdx.x >> 6);
    if (row >= N_NODES) return;
    int lane = threadIdx.x & 63;
    int li = lane & 15;
    int sub = lane >> 4;

    int b = st.rp[row], e = st.rp[row + 1];
    float acc[8] = {0.f, 0.f, 0.f, 0.f, 0.f, 0.f, 0.f, 0.f};

    const char* gbase = (const char*)st.g16 + li * 16;

    int i = b + sub;
    // 4-deep batch: issue all cv reads, then all gathers, then consume
    for (; i + 12 < e; i += 16) {
        int2 c0 = st.cv[i];
        int2 c1 = st.cv[i + 4];
        int2 c2 = st.cv[i + 8];
        int2 c3 = st.cv[i + 12];
        uint4 w0 = *(const uint4*)(gbase + (unsigned)c0.x);
        uint4 w1 = *(const uint4*)(gbase + (unsigned)c1.x);
        uint4 w2 = *(const uint4*)(gbase + (unsigned)c2.x);
        uint4 w3 = *(const uint4*)(gbase + (unsigned)c3.x);
        sp_accum(acc, w0, __int_as_float(c0.y));
        sp_accum(acc, w1, __int_as_float(c1.y));
        sp_accum(acc, w2, __int_as_float(c2.y));
        sp_accum(acc, w3, __int_as_float(c3.y));
    }
    for (; i + 4 < e; i += 8) {
        int2 c0 = st.cv[i];
        int2 c1 = st.cv[i + 4];
        uint4 w0 = *(const uint4*)(gbase + (unsigned)c0.x);
        uint4 w1 = *(const uint4*)(gbase + (unsigned)c1.x);
        sp_accum(acc, w0, __int_as_float(c0.y));
        sp_accum(acc, w1, __int_as_float(c1.y));
    }
    if (i < e) {
        int2 c = st.cv[i];
        uint4 w = *(const uint4*)(gbase + (unsigned)c.x);
        sp_accum(acc, w, __int_as_float(c.y));
    }

    #pragma unroll
    for (int j = 0; j < 8; ++j) {
        acc[j] += __shfl_xor(acc[j], 16, 64);
        acc[j] += __shfl_xor(acc[j], 32, 64);
    }

    int o = row * 16 + li;       // uint4 index
    uint4 sv4 = ((const uint4*)st.s16)[o];
    float2 s0 = unpack2bf(sv4.x), s1 = unpack2bf(sv4.y);
    float2 s2 = unpack2bf(sv4.z), s3 = unpack2bf(sv4.w);
    float m[8] = {acc[0]*s0.x, acc[1]*s0.y, acc[2]*s1.x, acc[3]*s1.y,
                  acc[4]*s2.x, acc[5]*s2.y, acc[6]*s3.x, acc[7]*s3.y};

    if (sub == 0 && st.a16) {
        float a[8] = {acc[0], acc[1], acc[2], acc[3], acc[4], acc[5], acc[6], acc[7]};
        if (st.pa16) {
            uint4 pv = ((const uint4*)st.pa16)[o];
            float2 p0 = unpack2bf(pv.x), p1 = unpack2bf(pv.y);
            float2 p2 = unpack2bf(pv.z), p3 = unpack2bf(pv.w);
            a[0] += p0.x; a[1] += p0.y; a[2] += p1.x; a[3] += p1.y;
            a[4] += p2.x; a[5] += p2.y; a[6] += p3.x; a[7] += p3.y;
        }
        uint4 o4 = make_uint4(pack2bf(a[0], a[1]), pack2bf(a[2], a[3]),
                              pack2bf(a[4], a[5]), pack2bf(a[6], a[7]));
        ((uint4*)st.a16)[o] = o4;
    } else if (sub == 1 && st.m16) {
        float q[8] = {m[0], m[1], m[2], m[3], m[4], m[5], m[6], m[7]};
        if (st.pm16) {
            uint4 pv = ((const uint4*)st.pm16)[o];
            float2 p0 = unpack2bf(pv.x), p1 = unpack2bf(pv.y);
            float2 p2 = unpack2bf(pv.z), p3 = unpack2bf(pv.w);
            q[0] += p0.x; q[1] += p0.y; q[2] += p1.x; q[3] += p1.y;
            q[4] += p2.x; q[5] += p2.y; q[6] += p3.x; q[7] += p3.y;
        }
        uint4 o4 = make_uint4(pack2bf(q[0], q[1]), pack2bf(q[2], q[3]),
                              pack2bf(q[4], q[5]), pack2bf(q[6], q[7]));
        ((uint4*)st.m16)[o] = o4;
    } else if (sub == 2 && st.k16) {
        uint4 o4 = make_uint4(pack2bf(acc[0]+m[0], acc[1]+m[1]),
                              pack2bf(acc[2]+m[2], acc[3]+m[3]),
                              pack2bf(acc[4]+m[4], acc[5]+m[5]),
                              pack2bf(acc[6]+m[6], acc[7]+m[7]));
        ((uint4*)st.k16)[o] = o4;
    }
}

// ===========================================================================
// MFMA double GEMM, fragment-linear conflict-free LDS, 128-row blocks
// (two 64-row halves reuse in-register W fragments):
//   res = relu( X1@W1^T + X2@W2^T + 2*(b1+b2) )
// Two sets per dispatch (blocks >= nA -> set B). 32 KB LDS.
// ===========================================================================
struct G2 {
    const unsigned short* X1[2];
    const unsigned short* X2[2];
    float* outf[2];
    unsigned short* o16[2];
};

__global__ __launch_bounds__(256) void gemm2f(
    G2 g, const float* __restrict__ W1, const float* __restrict__ W2,
    const float* __restrict__ b1, const float* __restrict__ b2, int nA)
{
    __shared__ unsigned short xs[2][64 * DIM];   // 32 KB

    int second = (int)blockIdx.x >= nA;
    int blk = blockIdx.x - second * nA;
    const int tid = threadIdx.x;

    const unsigned short* Xs0 = g.X1[second];
    const unsigned short* Xs1 = g.X2[second];
    float* outf = g.outf[second];
    unsigned short* o16 = g.o16[second];

    const int wv = tid >> 6;
    const int lane = tid & 63;
    const int lr = lane & 15;
    const int kgrp = lane >> 4;
    const int colbase = wv * 32;

    // W fragments in registers: col = colbase + nt*16 + lr, k = ks*32 + kgrp*8
    short8 wf[2][2][4];
    #pragma unroll
    for (int mat = 0; mat < 2; ++mat) {
        const float* W = mat ? W2 : W1;
        #pragma unroll
        for (int nt = 0; nt < 2; ++nt) {
            #pragma unroll
            for (int ks = 0; ks < 4; ++ks) {
                const float* wp = W + (size_t)(colbase + nt * 16 + lr) * DIM
                                    + ks * 32 + kgrp * 8;
                wf[mat][nt][ks] = pack_bf8(*(const float4*)wp,
                                           *(const float4*)(wp + 4));
            }
        }
    }

    float cb[2];
    #pragma unroll
    for (int nt = 0; nt < 2; ++nt) {
        int col = colbase + nt * 16 + lr;
        cb[nt] = 2.0f * (b1[col] + b2[col]);
    }

    #pragma unroll
    for (int h = 0; h < 2; ++h) {
        const int row0 = blk * 128 + h * 64;
        if (h) __syncthreads();      // xs reads of previous half done

        #pragma unroll
        for (int t = 0; t < 2; ++t) {
            const unsigned short* X = t ? Xs1 : Xs0;
            #pragma unroll
            for (int it = 0; it < 4; ++it) {
                int id = tid + 256 * it;
                int r = id >> 4, c16 = id & 15;
                int ks = c16 >> 2, kg = c16 & 3;
                int mt = r >> 4, rr = r & 15;
                int addr = ((((ks * 4 + mt) * 64) + kg * 16 + rr) * 16) ^ (ks << 5);
                int grow = min(row0 + r, N_NODES - 1);
                uint4 d = *(const uint4*)(X + (size_t)grow * DIM + c16 * 8);
                *(uint4*)((char*)&xs[t][0] + addr) = d;
            }
        }
        __syncthreads();

        f32x4 acc[4][2];
        #pragma unroll
        for (int mt = 0; mt < 4; ++mt)
            #pragma unroll
            for (int nt = 0; nt < 2; ++nt)
                acc[mt][nt] = (f32x4){0.f, 0.f, 0.f, 0.f};

        #pragma unroll
        for (int ks = 0; ks < 4; ++ks) {
            short8 a1f[4], a2f[4];
            #pragma unroll
            for (int mt = 0; mt < 4; ++mt) {
                int addr = ((((ks * 4 + mt) * 64) + lane) * 16) ^ (ks << 5);
                a1f[mt] = *(const short8*)((const char*)&xs[0][0] + addr);
                a2f[mt] = *(const short8*)((const char*)&xs[1][0] + addr);
            }
            #pragma unroll
            for (int mt = 0; mt < 4; ++mt) {
                #pragma unroll
                for (int nt = 0; nt < 2; ++nt) {
                    acc[mt][nt] = __builtin_amdgcn_mfma_f32_16x16x32_bf16(
                        a1f[mt], wf[0][nt][ks], acc[mt][nt], 0, 0, 0);
                    acc[mt][nt] = __builtin_amdgcn_mfma_f32_16x16x32_bf16(
                        a2f[mt], wf[1][nt][ks], acc[mt][nt], 0, 0, 0);
                }
            }
        }

        #pragma unroll
        for (int nt = 0; nt < 2; ++nt) {
            int col = colbase + nt * 16 + lr;
            #pragma unroll
            for (int mt = 0; mt < 4; ++mt) {
                #pragma unroll
                for (int r = 0; r < 4; ++r) {
                    int row = row0 + mt * 16 + kgrp * 4 + r;
                    if (row < N_NODES) {
                        float o = fmaxf(acc[mt][nt][r] + cb[nt], 0.f);
                        if (outf) outf[(size_t)row * DIM + col] = o;
                        if (o16) o16[(size_t)row * DIM + col] = f2bf(o);
                    }
                }
            }
        }
    }
}

// ===========================================================================
extern "C" void kernel_launch(void* const* d_in, const int* in_sizes, int n_in,
                              void* d_out, int out_size, void* d_ws, size_t ws_size,
                              hipStream_t stream)
{
    const float* l_feat = (const float*)d_in[0];
    const float* r_feat = (const float*)d_in[1];
    const int*   rows   = (const int*)d_in[2];
    const int*   cols   = (const int*)d_in[3];
    const float* vals   = (const float*)d_in[4];
    const float* W1a    = (const float*)d_in[5];
    const float* b1a    = (const float*)d_in[6];
    const float* W2a    = (const float*)d_in[7];
    const float* b2a    = (const float*)d_in[8];
    const float* W1b    = (const float*)d_in[9];
    const float* b1b    = (const float*)d_in[10];
    const float* W2b    = (const float*)d_in[11];
    const float* b2b    = (const float*)d_in[12];
    float* out = (float*)d_out;

    const size_t NT = (size_t)N_NODES * DIM;
    const size_t MAT16 = NT * 2;

    char* p = (char*)d_ws;
    auto alloc = [&](size_t bytes) {
        char* q = p; p += (bytes + 255) & ~(size_t)255; return q;
    };
    unsigned int* l16 = (unsigned int*)alloc(MAT16);   // l_feat -> y1
    unsigned int* r16 = (unsigned int*)alloc(MAT16);   // r_feat -> z1
    unsigned int* Kl  = (unsigned int*)alloc(MAT16);
    unsigned int* Kr  = (unsigned int*)alloc(MAT16);
    unsigned int* aL  = (unsigned int*)alloc(MAT16);   // a-sum (L)
    unsigned int* mL  = (unsigned int*)alloc(MAT16);   // m-sum (L)
    unsigned int* aR  = (unsigned int*)alloc(MAT16);   // a-sum (R)
    unsigned int* mR  = (unsigned int*)alloc(MAT16);   // m-sum (R)
    int* rpA = (int*)alloc((size_t)(N_NODES + 1) * 4);
    int* rpT = (int*)alloc((size_t)(N_NODES + 1) * 4);
    int* bktCnt  = (int*)alloc((size_t)(2 * NBKT) * 4);
    int* bktBase = (int*)alloc((size_t)(2 * NBKT) * 4);
    int2* cvA = (int2*)alloc((size_t)E_EDGES * 8);
    int2* cvT = (int2*)alloc((size_t)E_EDGES * 8);
    uint2* stagedA = (uint2*)alloc((size_t)NBKT * BKT_CAP * 8);
    uint2* stagedT = (uint2*)alloc((size_t)NBKT * BKT_CAP * 8);

    const int n4 = (int)(NT / 4);
    dim3 blk(256);
    dim3 cvGrid((n4 + 255) / 256);
    const int spBlocks = (N_NODES + 3) / 4;        // 10000
    const int gmBlocks = (N_NODES + 127) / 128;    // 313
    const int p1Blocks = (E_EDGES + 2047) / 2048;  // 313

    // ---- CSR build + bf16 conversion ----
    hipMemsetAsync(bktCnt, 0, (size_t)(2 * NBKT) * 4, stream);
    convert_kernel<<<cvGrid, blk, 0, stream>>>(
        (const float4*)l_feat, (const float4*)r_feat,
        (uint2*)l16, (uint2*)r16, n4);
    build_p1<<<dim3(p1Blocks), blk, 0, stream>>>(
        rows, cols, vals, bktCnt, stagedA, stagedT);
    bkt_scan<<<1, blk, 0, stream>>>(bktCnt, bktBase, rpA, rpT);
    build_p2<<<dim3(2 * NBKT), blk, 0, stream>>>(
        bktCnt, bktBase, stagedA, stagedT, rpA, rpT, cvA, cvT);

    // ======================= Layer A =======================
    {   // hop0: a0=A@r (store a,m,Kl) ; b0=AT@l (store a,m,Kr)
        SpSet h0A = {rpA, cvA, r16, l16, nullptr, nullptr, aL, mL, Kl};
        SpSet h0T = {rpT, cvT, l16, r16, nullptr, nullptr, aR, mR, Kr};
        sp_multi<<<dim3(2 * spBlocks), blk, 0, stream>>>(h0A, h0T, spBlocks);
    }
    {   // hop1 (accumulate in place): aL=bf(aL+t), mL=bf(mL+t*Kl); same for R
        SpSet h1A = {rpA, cvA, Kr, Kl, aL, mL, aL, mL, nullptr};
        SpSet h1T = {rpT, cvT, Kl, Kr, aR, mR, aR, mR, nullptr};
        sp_multi<<<dim3(2 * spBlocks), blk, 0, stream>>>(h1A, h1T, spBlocks);
    }
    {   // y1 -> l16 (bf16), z1 -> r16 (bf16)
        G2 g;
        g.X1[0] = (const unsigned short*)aL; g.X2[0] = (const unsigned short*)mL;
        g.X1[1] = (const unsigned short*)aR; g.X2[1] = (const unsigned short*)mR;
        g.outf[0] = nullptr; g.outf[1] = nullptr;
        g.o16[0] = (unsigned short*)l16;
        g.o16[1] = (unsigned short*)r16;
        gemm2f<<<dim3(2 * gmBlocks), blk, 0, stream>>>(
            g, W1a, W2a, b1a, b2a, gmBlocks);
    }

    // ======================= Layer B (l-output only) =======================
    {   // a=A@z1 (store a,m,Klb) ; b=AT@y1 (store Krb only)
        SpSet b0A = {rpA, cvA, r16, l16, nullptr, nullptr, aL, mL, Kl};
        SpSet b0T = {rpT, cvT, l16, r16, nullptr, nullptr, nullptr, nullptr, Kr};
        sp_multi<<<dim3(2 * spBlocks), blk, 0, stream>>>(b0A, b0T, spBlocks);
    }
    {   // hop1: aL=bf(aL+t), mL=bf(mL+t*Klb)
        SpSet b1A = {rpA, cvA, Kr, Kl, aL, mL, aL, mL, nullptr};
        sp_multi<<<dim3(spBlocks), blk, 0, stream>>>(b1A, b1A, spBlocks);
    }
    {   // out = relu(aL@W1b^T + mL@W2b^T + 2(b1b+b2b))  [fp32]
        G2 g;
        g.X1[0] = (const unsigned short*)aL; g.X2[0] = (const unsigned short*)mL;
        g.X1[1] = g.X1[0]; g.X2[1] = g.X2[0];
        g.outf[0] = out; g.outf[1] = nullptr;
        g.o16[0] = nullptr; g.o16[1] = nullptr;
        gemm2f<<<dim3(gmBlocks), blk, 0, stream>>>(
            g, W1b, W2b, b1b, b2b, gmBlocks);
    }
}

// Round 9
// 312.439 us; speedup vs baseline: 25.3646x; 1.0033x over previous
//
#include <hip/hip_runtime.h>

#define N_NODES 40000
#define E_EDGES 640000
#define DIM 128
#define NBKT 157            // buckets of 256 rows
#define BKT_CAP 6144

typedef __attribute__((ext_vector_type(8))) short short8;
typedef __attribute__((ext_vector_type(4))) float f32x4;

__device__ __forceinline__ unsigned short f2bf(float f) {
    unsigned int u = __float_as_uint(f);
    u = u + 0x7FFFu + ((u >> 16) & 1u);
    return (unsigned short)(u >> 16);
}
__device__ __forceinline__ unsigned int pack2bf(float lo, float hi) {
    return (unsigned int)f2bf(lo) | ((unsigned int)f2bf(hi) << 16);
}
__device__ __forceinline__ float2 unpack2bf(unsigned int u) {
    return make_float2(__uint_as_float(u << 16), __uint_as_float(u & 0xFFFF0000u));
}
__device__ __forceinline__ short8 pack_bf8(float4 a, float4 b) {
    short8 r;
    r[0] = (short)f2bf(a.x); r[1] = (short)f2bf(a.y);
    r[2] = (short)f2bf(a.z); r[3] = (short)f2bf(a.w);
    r[4] = (short)f2bf(b.x); r[5] = (short)f2bf(b.y);
    r[6] = (short)f2bf(b.z); r[7] = (short)f2bf(b.w);
    return r;
}

// ===========================================================================
// fp32 -> bf16 feature conversion
// ===========================================================================
__global__ __launch_bounds__(256) void convert_kernel(
    const float4* __restrict__ lf, const float4* __restrict__ rf,
    uint2* __restrict__ l16, uint2* __restrict__ r16, int n4)
{
    int i = blockIdx.x * 256 + threadIdx.x;
    if (i >= n4) return;
    float4 a = lf[i];
    float4 b = rf[i];
    l16[i] = make_uint2(pack2bf(a.x, a.y), pack2bf(a.z, a.w));
    r16[i] = make_uint2(pack2bf(b.x, b.y), pack2bf(b.z, b.w));
}

// ===========================================================================
// CSR build phase 1: LDS-aggregated bucket partition (both directions)
// ===========================================================================
__global__ __launch_bounds__(256) void build_p1(
    const int* __restrict__ rows, const int* __restrict__ cols,
    const float* __restrict__ vals,
    int* __restrict__ bktCnt,
    uint2* __restrict__ stagedA, uint2* __restrict__ stagedT)
{
    __shared__ int cA[NBKT], cT[NBKT], bA[NBKT], bT[NBKT];
    const int tid = threadIdx.x;
    for (int i = tid; i < NBKT; i += 256) { cA[i] = 0; cT[i] = 0; }
    __syncthreads();

    int r[8], c[8];
    unsigned int v[8];
    const int base = blockIdx.x * 2048 + tid;
    #pragma unroll
    for (int k = 0; k < 8; ++k) {
        int e = base + k * 256;
        bool ok = e < E_EDGES;
        r[k] = ok ? __builtin_nontemporal_load(rows + e) : -1;
        c[k] = ok ? __builtin_nontemporal_load(cols + e) : 0;
        v[k] = ok ? __float_as_uint(__builtin_nontemporal_load(vals + e)) : 0u;
        if (ok) {
            atomicAdd(&cA[r[k] >> 8], 1);
            atomicAdd(&cT[c[k] >> 8], 1);
        }
    }
    __syncthreads();
    for (int i = tid; i < NBKT; i += 256) {
        bA[i] = atomicAdd(&bktCnt[i], cA[i]);
        bT[i] = atomicAdd(&bktCnt[NBKT + i], cT[i]);
        cA[i] = 0; cT[i] = 0;
    }
    __syncthreads();
    #pragma unroll
    for (int k = 0; k < 8; ++k) {
        if (r[k] < 0) continue;
        int ba = r[k] >> 8;
        int pa = bA[ba] + atomicAdd(&cA[ba], 1);
        if (pa < BKT_CAP) {
            unsigned long long rec =
                ((unsigned long long)v[k] << 32) |
                (((unsigned)r[k] << 16) | (unsigned)c[k]);
            __builtin_nontemporal_store(rec,
                (unsigned long long*)(stagedA + (size_t)ba * BKT_CAP + pa));
        }
        int bt = c[k] >> 8;
        int pt = bT[bt] + atomicAdd(&cT[bt], 1);
        if (pt < BKT_CAP) {
            unsigned long long rec =
                ((unsigned long long)v[k] << 32) |
                (((unsigned)c[k] << 16) | (unsigned)r[k]);
            __builtin_nontemporal_store(rec,
                (unsigned long long*)(stagedT + (size_t)bt * BKT_CAP + pt));
        }
    }
}

__global__ __launch_bounds__(256) void bkt_scan(
    const int* __restrict__ bktCnt, int* __restrict__ bktBase,
    int* __restrict__ rpA, int* __restrict__ rpT)
{
    __shared__ int s[2][256];
    const int tid = threadIdx.x;
    for (int d = 0; d < 2; ++d) {
        int v = (tid < NBKT) ? min(bktCnt[d * NBKT + tid], BKT_CAP) : 0;
        s[0][tid] = v;
        __syncthreads();
        int sel = 0;
        for (int off = 1; off < 256; off <<= 1) {
            int t = s[sel][tid] + ((tid >= off) ? s[sel][tid - off] : 0);
            s[sel ^ 1][tid] = t;
            sel ^= 1;
            __syncthreads();
        }
        int incl = s[sel][tid];
        if (tid < NBKT) bktBase[d * NBKT + tid] = incl - v;
        if (tid == NBKT - 1) (d ? rpT : rpA)[N_NODES] = incl;
        __syncthreads();
    }
}

__global__ __launch_bounds__(256) void build_p2(
    const int* __restrict__ bktCnt, const int* __restrict__ bktBase,
    const uint2* __restrict__ stagedA, const uint2* __restrict__ stagedT,
    int* __restrict__ rpA, int* __restrict__ rpT,
    int2* __restrict__ cvA, int2* __restrict__ cvT)
{
    const int tid = threadIdx.x;
    int dir = (int)blockIdx.x >= NBKT;
    int b = blockIdx.x - dir * NBKT;
    int cnt = min(bktCnt[dir * NBKT + b], BKT_CAP);
    int cbase = bktBase[dir * NBKT + b];
    const uint2* staged = (dir ? stagedT : stagedA) + (size_t)b * BKT_CAP;
    int* rp = dir ? rpT : rpA;
    int2* cv = dir ? cvT : cvA;

    __shared__ int rc[256];
    __shared__ int s[2][256];
    rc[tid] = 0;
    __syncthreads();
    for (int i = tid; i < cnt; i += 256)
        atomicAdd(&rc[(staged[i].x >> 16) & 255], 1);
    __syncthreads();
    int own = rc[tid];
    s[0][tid] = own;
    __syncthreads();
    int sel = 0;
    for (int off = 1; off < 256; off <<= 1) {
        int t = s[sel][tid] + ((tid >= off) ? s[sel][tid - off] : 0);
        s[sel ^ 1][tid] = t;
        sel ^= 1;
        __syncthreads();
    }
    int ex = s[sel][tid] - own;
    int row = b * 256 + tid;
    if (row < N_NODES) rp[row] = cbase + ex;
    rc[tid] = ex;
    __syncthreads();
    for (int i = tid; i < cnt; i += 256) {
        uint2 rec = staged[i];
        int local = (rec.x >> 16) & 255;
        int pos = cbase + atomicAdd(&rc[local], 1);
        // store col as BYTE offset (col * 256) for cheap gather addressing
        cv[pos] = make_int2((int)((rec.x & 0xFFFFu) << 8), (int)rec.y);
    }
}

// ===========================================================================
// Generic SpMM: 16 lanes/edge, 16B/lane, 4 edge sub-streams, 4-deep gather
// batch with FORCED liveness (reverse-order consume + sched_group_barrier)
// so 16 random gathers per wave are genuinely in flight.
//   t = M @ g16 ; m = t * s16
// Optional prior accumulation: a = pa + t, q = pm + m (in-place safe).
// Stores (nullable): a16 = bf(a), m16 = bf(q), k16 = bf(t + m).
// cv.x holds col*256 (byte offset). Two sets per dispatch (blocks>=nA -> B).
// ===========================================================================
struct SpSet {
    const int* rp;
    const int2* cv;
    const unsigned int* g16;
    const unsigned int* s16;
    const unsigned int* pa16;   // prior a (or null)
    const unsigned int* pm16;   // prior m (or null)
    unsigned int* a16;
    unsigned int* m16;
    unsigned int* k16;
};

__device__ __forceinline__ void sp_accum(float* acc, uint4 w, float v) {
    float2 f;
    f = unpack2bf(w.x); acc[0] = fmaf(v, f.x, acc[0]); acc[1] = fmaf(v, f.y, acc[1]);
    f = unpack2bf(w.y); acc[2] = fmaf(v, f.x, acc[2]); acc[3] = fmaf(v, f.y, acc[3]);
    f = unpack2bf(w.z); acc[4] = fmaf(v, f.x, acc[4]); acc[5] = fmaf(v, f.y, acc[5]);
    f = unpack2bf(w.w); acc[6] = fmaf(v, f.x, acc[6]); acc[7] = fmaf(v, f.y, acc[7]);
}

__global__ __launch_bounds__(256) void sp_multi(SpSet sA, SpSet sB, int nA)
{
    bool second = (int)blockIdx.x >= nA;
    SpSet st = second ? sB : sA;
    int blk = second ? (blockIdx.x - nA) : blockIdx.x;
    int row = blk * 4 + (threadIdx.x >> 6);
    if (row >= N_NODES) return;
    int lane = threadIdx.x & 63;
    int li = lane & 15;
    int sub = lane >> 4;

    int b = st.rp[row], e = st.rp[row + 1];
    int o = row * 16 + li;       // uint4 index
    // issue the row-local companion read early; overlaps the gather loop
    uint4 sv4 = ((const uint4*)st.s16)[o];

    float acc[8] = {0.f, 0.f, 0.f, 0.f, 0.f, 0.f, 0.f, 0.f};
    const char* gbase = (const char*)st.g16 + li * 16;

    int i = b + sub;
    // 4-deep batch; reverse-order consumption forbids register recycling,
    // so all 4 gathers (16 per wave) stay in flight.
    for (; i + 12 < e; i += 16) {
        int2 c0 = st.cv[i];
        int2 c1 = st.cv[i + 4];
        int2 c2 = st.cv[i + 8];
        int2 c3 = st.cv[i + 12];
        uint4 w0 = *(const uint4*)(gbase + (unsigned)c0.x);
        uint4 w1 = *(const uint4*)(gbase + (unsigned)c1.x);
        uint4 w2 = *(const uint4*)(gbase + (unsigned)c2.x);
        uint4 w3 = *(const uint4*)(gbase + (unsigned)c3.x);
        __builtin_amdgcn_sched_group_barrier(0x20, 8, 0);   // 8 VMEM reads first
        sp_accum(acc, w3, __int_as_float(c3.y));
        sp_accum(acc, w2, __int_as_float(c2.y));
        sp_accum(acc, w1, __int_as_float(c1.y));
        sp_accum(acc, w0, __int_as_float(c0.y));
    }
    for (; i + 4 < e; i += 8) {
        int2 c0 = st.cv[i];
        int2 c1 = st.cv[i + 4];
        uint4 w0 = *(const uint4*)(gbase + (unsigned)c0.x);
        uint4 w1 = *(const uint4*)(gbase + (unsigned)c1.x);
        __builtin_amdgcn_sched_group_barrier(0x20, 4, 0);
        sp_accum(acc, w1, __int_as_float(c1.y));
        sp_accum(acc, w0, __int_as_float(c0.y));
    }
    if (i < e) {
        int2 c = st.cv[i];
        uint4 w = *(const uint4*)(gbase + (unsigned)c.x);
        sp_accum(acc, w, __int_as_float(c.y));
    }

    #pragma unroll
    for (int j = 0; j < 8; ++j) {
        acc[j] += __shfl_xor(acc[j], 16, 64);
        acc[j] += __shfl_xor(acc[j], 32, 64);
    }

    float2 s0 = unpack2bf(sv4.x), s1 = unpack2bf(sv4.y);
    float2 s2 = unpack2bf(sv4.z), s3 = unpack2bf(sv4.w);
    float m[8] = {acc[0]*s0.x, acc[1]*s0.y, acc[2]*s1.x, acc[3]*s1.y,
                  acc[4]*s2.x, acc[5]*s2.y, acc[6]*s3.x, acc[7]*s3.y};

    if (sub == 0 && st.a16) {
        float a[8] = {acc[0], acc[1], acc[2], acc[3], acc[4], acc[5], acc[6], acc[7]};
        if (st.pa16) {
            uint4 pv = ((const uint4*)st.pa16)[o];
            float2 p0 = unpack2bf(pv.x), p1 = unpack2bf(pv.y);
            float2 p2 = unpack2bf(pv.z), p3 = unpack2bf(pv.w);
            a[0] += p0.x; a[1] += p0.y; a[2] += p1.x; a[3] += p1.y;
            a[4] += p2.x; a[5] += p2.y; a[6] += p3.x; a[7] += p3.y;
        }
        uint4 o4 = make_uint4(pack2bf(a[0], a[1]), pack2bf(a[2], a[3]),
                              pack2bf(a[4], a[5]), pack2bf(a[6], a[7]));
        ((uint4*)st.a16)[o] = o4;
    } else if (sub == 1 && st.m16) {
        float q[8] = {m[0], m[1], m[2], m[3], m[4], m[5], m[6], m[7]};
        if (st.pm16) {
            uint4 pv = ((const uint4*)st.pm16)[o];
            float2 p0 = unpack2bf(pv.x), p1 = unpack2bf(pv.y);
            float2 p2 = unpack2bf(pv.z), p3 = unpack2bf(pv.w);
            q[0] += p0.x; q[1] += p0.y; q[2] += p1.x; q[3] += p1.y;
            q[4] += p2.x; q[5] += p2.y; q[6] += p3.x; q[7] += p3.y;
        }
        uint4 o4 = make_uint4(pack2bf(q[0], q[1]), pack2bf(q[2], q[3]),
                              pack2bf(q[4], q[5]), pack2bf(q[6], q[7]));
        ((uint4*)st.m16)[o] = o4;
    } else if (sub == 2 && st.k16) {
        uint4 o4 = make_uint4(pack2bf(acc[0]+m[0], acc[1]+m[1]),
                              pack2bf(acc[2]+m[2], acc[3]+m[3]),
                              pack2bf(acc[4]+m[4], acc[5]+m[5]),
                              pack2bf(acc[6]+m[6], acc[7]+m[7]));
        ((uint4*)st.k16)[o] = o4;
    }
}

// ===========================================================================
// MFMA double GEMM, fragment-linear conflict-free LDS, 128-row blocks
// (two 64-row halves reuse in-register W fragments):
//   res = relu( X1@W1^T + X2@W2^T + 2*(b1+b2) )
// Two sets per dispatch (blocks >= nA -> set B). 32 KB LDS.
// ===========================================================================
struct G2 {
    const unsigned short* X1[2];
    const unsigned short* X2[2];
    float* outf[2];
    unsigned short* o16[2];
};

__global__ __launch_bounds__(256) void gemm2f(
    G2 g, const float* __restrict__ W1, const float* __restrict__ W2,
    const float* __restrict__ b1, const float* __restrict__ b2, int nA)
{
    __shared__ unsigned short xs[2][64 * DIM];   // 32 KB

    int second = (int)blockIdx.x >= nA;
    int blk = blockIdx.x - second * nA;
    const int tid = threadIdx.x;

    const unsigned short* Xs0 = g.X1[second];
    const unsigned short* Xs1 = g.X2[second];
    float* outf = g.outf[second];
    unsigned short* o16 = g.o16[second];

    const int wv = tid >> 6;
    const int lane = tid & 63;
    const int lr = lane & 15;
    const int kgrp = lane >> 4;
    const int colbase = wv * 32;

    // W fragments in registers: col = colbase + nt*16 + lr, k = ks*32 + kgrp*8
    short8 wf[2][2][4];
    #pragma unroll
    for (int mat = 0; mat < 2; ++mat) {
        const float* W = mat ? W2 : W1;
        #pragma unroll
        for (int nt = 0; nt < 2; ++nt) {
            #pragma unroll
            for (int ks = 0; ks < 4; ++ks) {
                const float* wp = W + (size_t)(colbase + nt * 16 + lr) * DIM
                                    + ks * 32 + kgrp * 8;
                wf[mat][nt][ks] = pack_bf8(*(const float4*)wp,
                                           *(const float4*)(wp + 4));
            }
        }
    }

    float cb[2];
    #pragma unroll
    for (int nt = 0; nt < 2; ++nt) {
        int col = colbase + nt * 16 + lr;
        cb[nt] = 2.0f * (b1[col] + b2[col]);
    }

    #pragma unroll
    for (int h = 0; h < 2; ++h) {
        const int row0 = blk * 128 + h * 64;
        if (h) __syncthreads();      // xs reads of previous half done

        #pragma unroll
        for (int t = 0; t < 2; ++t) {
            const unsigned short* X = t ? Xs1 : Xs0;
            #pragma unroll
            for (int it = 0; it < 4; ++it) {
                int id = tid + 256 * it;
                int r = id >> 4, c16 = id & 15;
                int ks = c16 >> 2, kg = c16 & 3;
                int mt = r >> 4, rr = r & 15;
                int addr = ((((ks * 4 + mt) * 64) + kg * 16 + rr) * 16) ^ (ks << 5);
                int grow = min(row0 + r, N_NODES - 1);
                uint4 d = *(const uint4*)(X + (size_t)grow * DIM + c16 * 8);
                *(uint4*)((char*)&xs[t][0] + addr) = d;
            }
        }
        __syncthreads();

        f32x4 acc[4][2];
        #pragma unroll
        for (int mt = 0; mt < 4; ++mt)
            #pragma unroll
            for (int nt = 0; nt < 2; ++nt)
                acc[mt][nt] = (f32x4){0.f, 0.f, 0.f, 0.f};

        #pragma unroll
        for (int ks = 0; ks < 4; ++ks) {
            short8 a1f[4], a2f[4];
            #pragma unroll
            for (int mt = 0; mt < 4; ++mt) {
                int addr = ((((ks * 4 + mt) * 64) + lane) * 16) ^ (ks << 5);
                a1f[mt] = *(const short8*)((const char*)&xs[0][0] + addr);
                a2f[mt] = *(const short8*)((const char*)&xs[1][0] + addr);
            }
            #pragma unroll
            for (int mt = 0; mt < 4; ++mt) {
                #pragma unroll
                for (int nt = 0; nt < 2; ++nt) {
                    acc[mt][nt] = __builtin_amdgcn_mfma_f32_16x16x32_bf16(
                        a1f[mt], wf[0][nt][ks], acc[mt][nt], 0, 0, 0);
                    acc[mt][nt] = __builtin_amdgcn_mfma_f32_16x16x32_bf16(
                        a2f[mt], wf[1][nt][ks], acc[mt][nt], 0, 0, 0);
                }
            }
        }

        #pragma unroll
        for (int nt = 0; nt < 2; ++nt) {
            int col = colbase + nt * 16 + lr;
            #pragma unroll
            for (int mt = 0; mt < 4; ++mt) {
                #pragma unroll
                for (int r = 0; r < 4; ++r) {
                    int row = row0 + mt * 16 + kgrp * 4 + r;
                    if (row < N_NODES) {
                        float o = fmaxf(acc[mt][nt][r] + cb[nt], 0.f);
                        if (outf) outf[(size_t)row * DIM + col] = o;
                        if (o16) o16[(size_t)row * DIM + col] = f2bf(o);
                    }
                }
            }
        }
    }
}

// ===========================================================================
extern "C" void kernel_launch(void* const* d_in, const int* in_sizes, int n_in,
                              void* d_out, int out_size, void* d_ws, size_t ws_size,
                              hipStream_t stream)
{
    const float* l_feat = (const float*)d_in[0];
    const float* r_feat = (const float*)d_in[1];
    const int*   rows   = (const int*)d_in[2];
    const int*   cols   = (const int*)d_in[3];
    const float* vals   = (const float*)d_in[4];
    const float* W1a    = (const float*)d_in[5];
    const float* b1a    = (const float*)d_in[6];
    const float* W2a    = (const float*)d_in[7];
    const float* b2a    = (const float*)d_in[8];
    const float* W1b    = (const float*)d_in[9];
    const float* b1b    = (const float*)d_in[10];
    const float* W2b    = (const float*)d_in[11];
    const float* b2b    = (const float*)d_in[12];
    float* out = (float*)d_out;

    const size_t NT = (size_t)N_NODES * DIM;
    const size_t MAT16 = NT * 2;

    char* p = (char*)d_ws;
    auto alloc = [&](size_t bytes) {
        char* q = p; p += (bytes + 255) & ~(size_t)255; return q;
    };
    unsigned int* l16 = (unsigned int*)alloc(MAT16);   // l_feat -> y1
    unsigned int* r16 = (unsigned int*)alloc(MAT16);   // r_feat -> z1
    unsigned int* Kl  = (unsigned int*)alloc(MAT16);
    unsigned int* Kr  = (unsigned int*)alloc(MAT16);
    unsigned int* aL  = (unsigned int*)alloc(MAT16);   // a-sum (L)
    unsigned int* mL  = (unsigned int*)alloc(MAT16);   // m-sum (L)
    unsigned int* aR  = (unsigned int*)alloc(MAT16);   // a-sum (R)
    unsigned int* mR  = (unsigned int*)alloc(MAT16);   // m-sum (R)
    int* rpA = (int*)alloc((size_t)(N_NODES + 1) * 4);
    int* rpT = (int*)alloc((size_t)(N_NODES + 1) * 4);
    int* bktCnt  = (int*)alloc((size_t)(2 * NBKT) * 4);
    int* bktBase = (int*)alloc((size_t)(2 * NBKT) * 4);
    int2* cvA = (int2*)alloc((size_t)E_EDGES * 8);
    int2* cvT = (int2*)alloc((size_t)E_EDGES * 8);
    uint2* stagedA = (uint2*)alloc((size_t)NBKT * BKT_CAP * 8);
    uint2* stagedT = (uint2*)alloc((size_t)NBKT * BKT_CAP * 8);

    const int n4 = (int)(NT / 4);
    dim3 blk(256);
    dim3 cvGrid((n4 + 255) / 256);
    const int spBlocks = (N_NODES + 3) / 4;        // 10000
    const int gmBlocks = (N_NODES + 127) / 128;    // 313
    const int p1Blocks = (E_EDGES + 2047) / 2048;  // 313

    // ---- CSR build + bf16 conversion ----
    hipMemsetAsync(bktCnt, 0, (size_t)(2 * NBKT) * 4, stream);
    convert_kernel<<<cvGrid, blk, 0, stream>>>(
        (const float4*)l_feat, (const float4*)r_feat,
        (uint2*)l16, (uint2*)r16, n4);
    build_p1<<<dim3(p1Blocks), blk, 0, stream>>>(
        rows, cols, vals, bktCnt, stagedA, stagedT);
    bkt_scan<<<1, blk, 0, stream>>>(bktCnt, bktBase, rpA, rpT);
    build_p2<<<dim3(2 * NBKT), blk, 0, stream>>>(
        bktCnt, bktBase, stagedA, stagedT, rpA, rpT, cvA, cvT);

    // ======================= Layer A =======================
    {   // hop0: a0=A@r (store a,m,Kl) ; b0=AT@l (store a,m,Kr)
        SpSet h0A = {rpA, cvA, r16, l16, nullptr, nullptr, aL, mL, Kl};
        SpSet h0T = {rpT, cvT, l16, r16, nullptr, nullptr, aR, mR, Kr};
        sp_multi<<<dim3(2 * spBlocks), blk, 0, stream>>>(h0A, h0T, spBlocks);
    }
    {   // hop1 (accumulate in place): aL=bf(aL+t), mL=bf(mL+t*Kl); same for R
        SpSet h1A = {rpA, cvA, Kr, Kl, aL, mL, aL, mL, nullptr};
        SpSet h1T = {rpT, cvT, Kl, Kr, aR, mR, aR, mR, nullptr};
        sp_multi<<<dim3(2 * spBlocks), blk, 0, stream>>>(h1A, h1T, spBlocks);
    }
    {   // y1 -> l16 (bf16), z1 -> r16 (bf16)
        G2 g;
        g.X1[0] = (const unsigned short*)aL; g.X2[0] = (const unsigned short*)mL;
        g.X1[1] = (const unsigned short*)aR; g.X2[1] = (const unsigned short*)mR;
        g.outf[0] = nullptr; g.outf[1] = nullptr;
        g.o16[0] = (unsigned short*)l16;
        g.o16[1] = (unsigned short*)r16;
        gemm2f<<<dim3(2 * gmBlocks), blk, 0, stream>>>(
            g, W1a, W2a, b1a, b2a, gmBlocks);
    }

    // ======================= Layer B (l-output only) =======================
    {   // a=A@z1 (store a,m,Klb) ; b=AT@y1 (store Krb only)
        SpSet b0A = {rpA, cvA, r16, l16, nullptr, nullptr, aL, mL, Kl};
        SpSet b0T = {rpT, cvT, l16, r16, nullptr, nullptr, nullptr, nullptr, Kr};
        sp_multi<<<dim3(2 * spBlocks), blk, 0, stream>>>(b0A, b0T, spBlocks);
    }
    {   // hop1: aL=bf(aL+t), mL=bf(mL+t*Klb)
        SpSet b1A = {rpA, cvA, Kr, Kl, aL, mL, aL, mL, nullptr};
        sp_multi<<<dim3(spBlocks), blk, 0, stream>>>(b1A, b1A, spBlocks);
    }
    {   // out = relu(aL@W1b^T + mL@W2b^T + 2(b1b+b2b))  [fp32]
        G2 g;
        g.X1[0] = (const unsigned short*)aL; g.X2[0] = (const unsigned short*)mL;
        g.X1[1] = g.X1[0]; g.X2[1] = g.X2[0];
        g.outf[0] = out; g.outf[1] = nullptr;
        g.o16[0] = nullptr; g.o16[1] = nullptr;
        gemm2f<<<dim3(gmBlocks), blk, 0, stream>>>(
            g, W1b, W2b, b1b, b2b, gmBlocks);
    }
}